// Round 2
// baseline (367.948 us; speedup 1.0000x reference)
//
#include <hip/hip_runtime.h>
#include <math.h>

#define NPTS   12800
#define P_PIX  2560
#define NC     32          // compositing chunks (NPTS/NC = 400 pts/chunk)
#define CHUNK  400
#define RANK_CHUNK 800
#define MLP_PITCH 264      // ushorts per LDS row (256 + 8 pad)

typedef short short8 __attribute__((ext_vector_type(8)));
typedef float f32x4 __attribute__((ext_vector_type(4)));

__device__ __forceinline__ unsigned short f2bf(float f) {
    unsigned int u = __float_as_uint(f);
    u += 0x7fffu + ((u >> 16) & 1u);   // RNE
    return (unsigned short)(u >> 16);
}

// ---------------------------------------------------------------- init
__global__ __launch_bounds__(256) void init_kernel(int* rnk, float* out, int n) {
    int i = blockIdx.x * 256 + threadIdx.x;
    if (i < n) rnk[i] = 0;
    if (i == 0) out[0] = 0.0f;
}

// ---------------------------------------------------------------- per-point projection
__global__ __launch_bounds__(256) void prep_kernel(
    const float* __restrict__ xyz, const float* __restrict__ scales,
    const float* __restrict__ rots, const float* __restrict__ opacity,
    const float* __restrict__ viewmat, const float* __restrict__ intrins,
    unsigned long long* __restrict__ keys,
    float* __restrict__ pu, float* __restrict__ pv, float* __restrict__ prad,
    float* __restrict__ phA, float* __restrict__ phC, float* __restrict__ pnB,
    float* __restrict__ pop, int N) {
    int cam = blockIdx.y;
    int i = blockIdx.x * 256 + threadIdx.x;
    if (i >= N) return;
    const float* vm = viewmat + cam * 16;
    const float* it = intrins + cam * 4;
    float fx = it[0], fy = it[1], cx = it[2], cy = it[3];
    float R00 = vm[0], R01 = vm[1], R02 = vm[2], t0 = vm[3];
    float R10 = vm[4], R11 = vm[5], R12 = vm[6], t1 = vm[7];
    float R20 = vm[8], R21 = vm[9], R22 = vm[10], t2 = vm[11];
    float X = xyz[i * 3], Y = xyz[i * 3 + 1], Z = xyz[i * 3 + 2];
    float x = R00 * X + R01 * Y + R02 * Z + t0;
    float y = R10 * X + R11 * Y + R12 * Z + t1;
    float z = R20 * X + R21 * Y + R22 * Z + t2;
    float zc = fmaxf(z, 0.001f);
    float iz = 1.0f / zc;
    float u = fx * x * iz + cx;
    float v = fy * y * iz + cy;
    float qw = rots[i * 4], qx = rots[i * 4 + 1], qy = rots[i * 4 + 2], qz = rots[i * 4 + 3];
    float qn = 1.0f / sqrtf(qw * qw + qx * qx + qy * qy + qz * qz);
    qw *= qn; qx *= qn; qy *= qn; qz *= qn;
    float s0 = expf(scales[i * 3]), s1 = expf(scales[i * 3 + 1]), s2 = expf(scales[i * 3 + 2]);
    float Rq[3][3] = {
        {1 - 2 * (qy * qy + qz * qz), 2 * (qx * qy - qw * qz), 2 * (qx * qz + qw * qy)},
        {2 * (qx * qy + qw * qz), 1 - 2 * (qx * qx + qz * qz), 2 * (qy * qz - qw * qx)},
        {2 * (qx * qz - qw * qy), 2 * (qy * qz + qw * qx), 1 - 2 * (qx * qx + qy * qy)}};
    float M[3][3];
    #pragma unroll
    for (int r = 0; r < 3; ++r) { M[r][0] = Rq[r][0] * s0; M[r][1] = Rq[r][1] * s1; M[r][2] = Rq[r][2] * s2; }
    float c3[3][3];
    #pragma unroll
    for (int a = 0; a < 3; ++a)
        #pragma unroll
        for (int b = 0; b < 3; ++b)
            c3[a][b] = M[a][0] * M[b][0] + M[a][1] * M[b][1] + M[a][2] * M[b][2];
    float Rw[3][3] = {{R00, R01, R02}, {R10, R11, R12}, {R20, R21, R22}};
    float Wt[3][3];
    #pragma unroll
    for (int a = 0; a < 3; ++a)
        #pragma unroll
        for (int b = 0; b < 3; ++b)
            Wt[a][b] = Rw[a][0] * c3[0][b] + Rw[a][1] * c3[1][b] + Rw[a][2] * c3[2][b];
    float cw[3][3];
    #pragma unroll
    for (int a = 0; a < 3; ++a)
        #pragma unroll
        for (int b = 0; b < 3; ++b)
            cw[a][b] = Wt[a][0] * Rw[b][0] + Wt[a][1] * Rw[b][1] + Wt[a][2] * Rw[b][2];
    float j00 = fx * iz, j02 = -fx * x * iz * iz;
    float j11 = fy * iz, j12 = -fy * y * iz * iz;
    float c00 = j00 * j00 * cw[0][0] + 2.0f * j00 * j02 * cw[0][2] + j02 * j02 * cw[2][2];
    float c01 = j00 * j11 * cw[0][1] + j00 * j12 * cw[0][2] + j02 * j11 * cw[2][1] + j02 * j12 * cw[2][2];
    float c11 = j11 * j11 * cw[1][1] + 2.0f * j11 * j12 * cw[1][2] + j12 * j12 * cw[2][2];
    float a = c00 + 0.3f, bq = c01, cc = c11 + 0.3f;
    float det = a * cc - bq * bq;
    float A = cc / det, Bc = -bq / det, Cc = a / det;
    // conservative cull radius: Q >= 0.5*lmin*r^2, drop alpha < 1e-8
    float lmin = 0.5f * ((A + Cc) - sqrtf((A - Cc) * (A - Cc) + 4.0f * Bc * Bc));
    lmin = fmaxf(lmin, 1e-20f);
    float opv = (z > 0.2f) ? opacity[i] : 0.0f;
    float rad = -1.0f;
    if (opv > 0.0f) {
        float tcut = logf(opv) + 18.42f;  // ln(op * 1e8)
        if (tcut > 0.0f) rad = sqrtf(2.0f * tcut / lmin);
    }
    int idx = cam * N + i;
    pu[idx] = u; pv[idx] = v; prad[idx] = rad;
    phA[idx] = -0.5f * A; phC[idx] = -0.5f * Cc; pnB[idx] = -Bc;
    pop[idx] = opv;
    unsigned int zb = __float_as_uint(z);
    zb = (zb & 0x80000000u) ? ~zb : (zb | 0x80000000u);
    keys[idx] = ((unsigned long long)zb << 32) | (unsigned int)i;
}

// ---------------------------------------------------------------- stable rank
__global__ __launch_bounds__(256) void rank_kernel(const unsigned long long* __restrict__ keys,
                                                   int* __restrict__ rnk, int N) {
    __shared__ unsigned long long sk[RANK_CHUNK];
    int cam = blockIdx.z;
    const unsigned long long* K = keys + (size_t)cam * N;
    int jbase = blockIdx.y * RANK_CHUNK;
    int jcnt = min(RANK_CHUNK, N - jbase);
    for (int t = threadIdx.x; t < jcnt; t += 256) sk[t] = K[jbase + t];
    __syncthreads();
    int i = blockIdx.x * 256 + threadIdx.x;
    if (i >= N) return;
    unsigned long long ki = K[i];
    int cnt = 0;
    #pragma unroll 8
    for (int j = 0; j < jcnt; ++j) cnt += (sk[j] < ki) ? 1 : 0;
    if (cnt) atomicAdd(rnk + (size_t)cam * N + i, cnt);
}

// ---------------------------------------------------------------- scatter into sorted records
// layout: [u, v, rad, hA, hC, nB, op, f0..f16] = 24 floats
__global__ __launch_bounds__(256) void scatter_kernel(
    const int* __restrict__ rnk,
    const float* __restrict__ pu, const float* __restrict__ pv, const float* __restrict__ prad,
    const float* __restrict__ phA, const float* __restrict__ phC, const float* __restrict__ pnB,
    const float* __restrict__ pop,
    const float* __restrict__ feats, float* __restrict__ rec, int N) {
    int cam = blockIdx.y;
    int i = blockIdx.x * 256 + threadIdx.x;
    if (i >= N) return;
    int idx = cam * N + i;
    int r = rnk[idx];
    float* d = rec + ((size_t)cam * N + r) * 24;
    d[0] = pu[idx]; d[1] = pv[idx]; d[2] = prad[idx];
    d[3] = phA[idx]; d[4] = phC[idx]; d[5] = pnB[idx]; d[6] = pop[idx];
    const float* f = feats + (size_t)i * 17;
    #pragma unroll
    for (int c = 0; c < 17; ++c) d[7 + c] = f[c];
}

// ---------------------------------------------------------------- chunked alpha compositing
// wave-uniform record reads (scalar-cache path) + wave-uniform y cull
__global__ __launch_bounds__(256) void splat_kernel(const float* __restrict__ rec,
                                                    float* __restrict__ part, int N) {
    int cam = blockIdx.z, ch = blockIdx.y;
    int p = blockIdx.x * 256 + threadIdx.x;
    float px = (float)(p & 63);
    float py = (float)(p >> 6);     // uniform per wave (64-aligned)
    const float* rbase = rec + ((size_t)cam * N + ch * CHUNK) * 24;
    float T = 1.0f;
    float acc[17];
    #pragma unroll
    for (int c = 0; c < 17; ++c) acc[c] = 0.0f;
    for (int n = 0; n < CHUNK; ++n) {
        const float* rp = rbase + n * 24;
        float u = rp[0], v = rp[1], rad = rp[2];
        if (fabsf(v - py) > rad + 0.01f) continue;   // wave-uniform skip
        float hA = rp[3], hC = rp[4], nB = rp[5], op = rp[6];
        float dx = u - px, dy = v - py;
        float power = (hA * dx) * dx;
        power = fmaf(hC * dy, dy, power);
        power = fmaf(nB * dx, dy, power);
        power = fminf(power, 0.0f);
        float alpha = fminf(0.99f, op * __expf(power));
        float w = alpha * T;
        #pragma unroll
        for (int c = 0; c < 17; ++c) acc[c] = fmaf(w, rp[7 + c], acc[c]);
        T *= (1.0f - alpha);
    }
    size_t base = ((size_t)(cam * NC + ch) * 18) * P_PIX + p;
    part[base] = T;
    #pragma unroll
    for (int c = 0; c < 17; ++c) part[base + (size_t)(1 + c) * P_PIX] = acc[c];
}

// ---------------------------------------------------------------- per-pixel transmittance prefix
__global__ __launch_bounds__(256) void tpref_kernel(const float* __restrict__ part,
                                                    float* __restrict__ tpref) {
    int cam = blockIdx.y;
    int p = blockIdx.x * 256 + threadIdx.x;
    float T = 1.0f;
    #pragma unroll 8
    for (int k = 0; k < NC; ++k) {
        tpref[((size_t)(cam * NC + k)) * P_PIX + p] = T;
        T *= part[((size_t)(cam * NC + k) * 18) * P_PIX + p];
    }
}

// ---------------------------------------------------------------- combine chunks -> fmap
__global__ __launch_bounds__(256) void combine_kernel(const float* __restrict__ part,
                                                      const float* __restrict__ tpref,
                                                      float* __restrict__ fmap) {
    int idx = blockIdx.x * 256 + threadIdx.x;
    if (idx >= 2 * 17 * P_PIX) return;
    int p = idx % P_PIX;
    int rem = idx / P_PIX;
    int c = rem % 17;
    int cam = rem / 17;
    float acc = 0.0f;
    #pragma unroll 8
    for (int k = 0; k < NC; ++k) {
        float Tp = tpref[((size_t)(cam * NC + k)) * P_PIX + p];
        float S = part[(((size_t)(cam * NC + k)) * 18 + 1 + c) * P_PIX + p];
        acc = fmaf(Tp, S, acc);
    }
    fmap[((size_t)cam * 17 + c) * P_PIX + p] = acc;
}

// ---------------------------------------------------------------- MLP: bf16 MFMA layer1 + fp32 L2/L3
__global__ __launch_bounds__(256, 1) void mlp_kernel(
    const float* __restrict__ embd, const float* __restrict__ sfeat,
    const float* __restrict__ W1, const float* __restrict__ b1,
    const float* __restrict__ g1, const float* __restrict__ be1,
    const float* __restrict__ W2, const float* __restrict__ b2,
    const float* __restrict__ g2, const float* __restrict__ be2,
    const float* __restrict__ W3, const float* __restrict__ b3,
    float* __restrict__ sed, float* __restrict__ ldf) {
    __shared__ unsigned short sX[64 * MLP_PITCH];   // [row][k] bf16, A-layout
    __shared__ unsigned short sW[64 * MLP_PITCH];   // [n][k]  bf16, B-layout (W1 as-is)
    __shared__ float sH[4][16 * 65];                // per-wave h (post-bias, pre-LN)
    int tid = threadIdx.x;
    int tile = blockIdx.x;
    const float* xbase;
    if (tile < 80) {           // sed tiles: 64 consecutive pixels, one source row ri
        int cam = tile / 40; int r = tile % 40;
        int ri = (r * 8) / 5;  // floor(r*64/40)
        xbase = embd + (size_t)cam * 256 * 4096 + ri * 64;
    } else {                   // ldf tiles: 64 consecutive t
        int tt = tile - 80; int cam = tt >> 6;
        xbase = sfeat + (size_t)cam * 256 * 4096 + (tt & 63) * 64;
    }
    const float4* xf4 = (const float4*)xbase;
    // stage X (coalesced over pixel dim, transpose into row-major bf16)
    for (int idx = tid; idx < 4096; idx += 256) {
        int k = idx >> 4, q = idx & 15;
        float4 xv = xf4[(size_t)k * 1024 + q];
        int r = q * 4;
        sX[(r + 0) * MLP_PITCH + k] = f2bf(xv.x);
        sX[(r + 1) * MLP_PITCH + k] = f2bf(xv.y);
        sX[(r + 2) * MLP_PITCH + k] = f2bf(xv.z);
        sX[(r + 3) * MLP_PITCH + k] = f2bf(xv.w);
    }
    // stage W1 (row-major already = B^T layout)
    const float4* wf4 = (const float4*)W1;
    for (int idx = tid; idx < 4096; idx += 256) {
        float4 wv = wf4[idx];
        int n = idx >> 6, kq = (idx & 63) * 4;
        uint2 pk;
        pk.x = (unsigned int)f2bf(wv.x) | ((unsigned int)f2bf(wv.y) << 16);
        pk.y = (unsigned int)f2bf(wv.z) | ((unsigned int)f2bf(wv.w) << 16);
        *(uint2*)&sW[n * MLP_PITCH + kq] = pk;
    }
    int lane = tid & 63, wv_ = tid >> 6;
    int c17 = lane < 17 ? lane : 16;
    // preload W2/W3 columns into registers (L1-cached strided reads, once per block)
    float w2c[64], w3c[64];
    #pragma unroll
    for (int k = 0; k < 64; ++k) w2c[k] = W2[lane * 64 + k];
    #pragma unroll
    for (int k = 0; k < 64; ++k) w3c[k] = W3[c17 * 64 + k];
    float g1l = g1[lane], be1l = be1[lane];
    float b2l = b2[lane], g2l = g2[lane], be2l = be2[lane];
    float b3l = b3[c17];
    __syncthreads();
    // ------- layer 1 MFMA: 16 rows x 64 outs per wave
    int rbase = wv_ * 16;
    int m = lane & 15, kq4 = lane >> 4;
    f32x4 acc[4];
    #pragma unroll
    for (int nt = 0; nt < 4; ++nt) acc[nt] = (f32x4){0.f, 0.f, 0.f, 0.f};
    const unsigned short* aptr = sX + (rbase + m) * MLP_PITCH + kq4 * 8;
    const unsigned short* bptr = sW + m * MLP_PITCH + kq4 * 8;
    #pragma unroll
    for (int ks = 0; ks < 8; ++ks) {
        short8 af = *(const short8*)(aptr + ks * 32);
        #pragma unroll
        for (int nt = 0; nt < 4; ++nt) {
            short8 bf = *(const short8*)(bptr + nt * 16 * MLP_PITCH + ks * 32);
            acc[nt] = __builtin_amdgcn_mfma_f32_16x16x32_bf16(af, bf, acc[nt], 0, 0, 0);
        }
    }
    // C layout: col = lane&15, row = (lane>>4)*4 + reg  -> write h+b1 to per-wave sH
    int q4 = kq4 * 4;
    #pragma unroll
    for (int nt = 0; nt < 4; ++nt) {
        float bv = b1[nt * 16 + m];
        #pragma unroll
        for (int rg = 0; rg < 4; ++rg)
            sH[wv_][(q4 + rg) * 65 + nt * 16 + m] = acc[nt][rg] + bv;
    }
    // ------- per-row LN1 / L2 / LN2 / L3 (fp32, register weights)
    for (int r = 0; r < 16; ++r) {
        float h = sH[wv_][r * 65 + lane];
        float s = h;
        #pragma unroll
        for (int o = 32; o; o >>= 1) s += __shfl_xor(s, o);
        float mu = s * (1.0f / 64.0f);
        float d = h - mu;
        float vs = d * d;
        #pragma unroll
        for (int o = 32; o; o >>= 1) vs += __shfl_xor(vs, o);
        float hn = d * (1.0f / sqrtf(vs * (1.0f / 64.0f) + 1e-5f)) * g1l + be1l;
        hn = fmaxf(hn, 0.01f * hn);
        float a2 = 0.0f;
        #pragma unroll
        for (int k = 0; k < 64; ++k) a2 = fmaf(__shfl(hn, k), w2c[k], a2);
        float h2 = a2 + b2l;
        s = h2;
        #pragma unroll
        for (int o = 32; o; o >>= 1) s += __shfl_xor(s, o);
        float mu2 = s * (1.0f / 64.0f);
        float d2 = h2 - mu2;
        float vs2 = d2 * d2;
        #pragma unroll
        for (int o = 32; o; o >>= 1) vs2 += __shfl_xor(vs2, o);
        float hn2 = d2 * (1.0f / sqrtf(vs2 * (1.0f / 64.0f) + 1e-5f)) * g2l + be2l;
        hn2 = fmaxf(hn2, 0.01f * hn2);
        float a3 = 0.0f;
        #pragma unroll
        for (int k = 0; k < 64; ++k) a3 = fmaf(__shfl(hn2, k), w3c[k], a3);
        float outv = a3 + b3l;
        if (lane < 17) {
            int row = tile * 64 + rbase + r;
            if (row < 5120) {
                int cam = row / 2560; int p = row - cam * 2560;
                sed[((size_t)cam * 2560 + p) * 17 + lane] = outv;
            } else {
                int rr = row - 5120; int cam = rr >> 12; int t = rr & 4095;
                ldf[((size_t)cam * 17 + lane) * 4096 + t] = outv;
            }
        }
    }
}

// ---------------------------------------------------------------- mask prototypes
__global__ __launch_bounds__(256) void proto_kernel(const float* __restrict__ masks,
                                                    const float* __restrict__ ldf,
                                                    float* __restrict__ proto) {
    int cam = blockIdx.y, m = blockIdx.x;
    const float* M = masks + ((size_t)cam * 16 + m) * 40000;
    float acc[18];
    #pragma unroll
    for (int j = 0; j < 18; ++j) acc[j] = 0.0f;
    for (int t = threadIdx.x; t < 4096; t += 256) {
        int h = t >> 6, w = t & 63;
        int rh = (h * 25) >> 3, rw = (w * 25) >> 3;
        float lv = M[rh * 200 + rw];
        if (lv != 0.0f) {
            acc[17] += lv;
            const float* L = ldf + (size_t)cam * 17 * 4096 + t;
            #pragma unroll
            for (int c = 0; c < 17; ++c) acc[c] = fmaf(lv, L[(size_t)c * 4096], acc[c]);
        }
    }
    __shared__ float red[4][18];
    int lane = threadIdx.x & 63, wv = threadIdx.x >> 6;
    #pragma unroll
    for (int j = 0; j < 18; ++j) {
        float v = acc[j];
        #pragma unroll
        for (int o = 32; o; o >>= 1) v += __shfl_xor(v, o);
        if (lane == 0) red[wv][j] = v;
    }
    __syncthreads();
    if (threadIdx.x < 17) {
        float sacc = red[0][threadIdx.x] + red[1][threadIdx.x] + red[2][threadIdx.x] + red[3][threadIdx.x];
        float ms = red[0][17] + red[1][17] + red[2][17] + red[3][17];
        proto[((size_t)cam * 16 + m) * 17 + threadIdx.x] = sacc / fmaxf(ms, 1e-6f);
    }
}

__device__ __forceinline__ void block_atomic_add(float v, float* target) {
    #pragma unroll
    for (int o = 32; o; o >>= 1) v += __shfl_xor(v, o);
    __shared__ float sred[4];
    int lane = threadIdx.x & 63, wv = threadIdx.x >> 6;
    if (lane == 0) sred[wv] = v;
    __syncthreads();
    if (threadIdx.x == 0) atomicAdd(target, sred[0] + sred[1] + sred[2] + sred[3]);
}

// ---------------------------------------------------------------- BCE loss
__global__ __launch_bounds__(256) void bce_kernel(const float* __restrict__ masks,
                                                  const float* __restrict__ proto,
                                                  const float* __restrict__ fmap,
                                                  float* __restrict__ out) {
    int idx = blockIdx.x * 256 + threadIdx.x;
    int p = idx % P_PIX;
    int rem = idx / P_PIX;
    int m = rem & 15, cam = rem >> 4;
    const float* pr = proto + ((size_t)cam * 16 + m) * 17;
    float sdot = 0;
    #pragma unroll
    for (int c = 0; c < 17; ++c)
        sdot = fmaf(pr[c], fmap[((size_t)cam * 17 + c) * P_PIX + p], sdot);
    float prob = 1.0f / (1.0f + expf(-sdot));
    int px = p & 63, py = p >> 6;
    float src_r = (py + 0.5f) * 5.0f - 0.5f;
    float src_c = (px + 0.5f) * 3.125f - 0.5f;
    int r0 = (int)fminf(fmaxf(floorf(src_r), 0.0f), 199.0f);
    int r1 = min(r0 + 1, 199);
    float wr = fminf(fmaxf(src_r - (float)r0, 0.0f), 1.0f);
    int c0 = (int)fminf(fmaxf(floorf(src_c), 0.0f), 199.0f);
    int c1 = min(c0 + 1, 199);
    float wc = fminf(fmaxf(src_c - (float)c0, 0.0f), 1.0f);
    const float* M = masks + ((size_t)cam * 16 + m) * 40000;
    float v00 = M[r0 * 200 + c0], v01 = M[r0 * 200 + c1];
    float v10 = M[r1 * 200 + c0], v11 = M[r1 * 200 + c1];
    float xr0 = v00 * (1.0f - wr) + v10 * wr;
    float xr1 = v01 * (1.0f - wr) + v11 * wr;
    float frm = xr0 * (1.0f - wc) + xr1 * wc;
    frm = (frm <= 0.5f) ? 0.0f : frm;
    float bce = frm * logf(prob + 1e-8f) + (1.0f - frm) * logf(1.0f - prob + 1e-8f);
    block_atomic_add(bce * (-1.0f / (16.0f * 2560.0f * 2.0f)), out);
}

// ---------------------------------------------------------------- L1 loss
__global__ __launch_bounds__(256) void l1_kernel(const float* __restrict__ fmap,
                                                 const float* __restrict__ sed,
                                                 float* __restrict__ out) {
    int idx = blockIdx.x * 256 + threadIdx.x;
    float ssum = 0;
    if (idx < 2 * P_PIX) {
        int p = idx % P_PIX, cam = idx / P_PIX;
        #pragma unroll
        for (int c = 0; c < 17; ++c) {
            float dv = fmap[((size_t)cam * 17 + c) * P_PIX + p] - sed[((size_t)cam * P_PIX + p) * 17 + c];
            ssum += fabsf(dv);
        }
    }
    block_atomic_add(ssum * (1.0f / (43520.0f * 2.0f)), out);
}

// ================================================================ launch
extern "C" void kernel_launch(void* const* d_in, const int* in_sizes, int n_in,
                              void* d_out, int out_size, void* d_ws, size_t ws_size,
                              hipStream_t stream) {
    const float* voxel_feats = (const float*)d_in[0];
    const float* opacity     = (const float*)d_in[1];
    const float* sam_embd    = (const float*)d_in[2];
    const float* sam_features= (const float*)d_in[3];
    const float* sam_masks   = (const float*)d_in[4];
    const float* viewmat     = (const float*)d_in[5];
    const float* intrins     = (const float*)d_in[6];
    const float* pc_xyz      = (const float*)d_in[7];
    const float* scales      = (const float*)d_in[8];
    const float* rots        = (const float*)d_in[9];
    const float* W1 = (const float*)d_in[10], *b1 = (const float*)d_in[11];
    const float* g1 = (const float*)d_in[12], *be1 = (const float*)d_in[13];
    const float* W2 = (const float*)d_in[14], *b2 = (const float*)d_in[15];
    const float* g2 = (const float*)d_in[16], *be2 = (const float*)d_in[17];
    const float* W3 = (const float*)d_in[18], *b3 = (const float*)d_in[19];
    float* out = (float*)d_out;
    const int N = in_sizes[7] / 3;  // 12800

    char* w = (char*)d_ws;
    size_t off = 0;
    auto alloc = [&](size_t bytes) -> void* {
        off = (off + 255) & ~(size_t)255;
        void* p = w + off; off += bytes; return p;
    };
    int* rnk  = (int*)alloc((size_t)2 * N * sizeof(int));
    unsigned long long* keys = (unsigned long long*)alloc((size_t)2 * N * 8);
    float* params = (float*)alloc((size_t)7 * 2 * N * 4);
    float* pu  = params,           *pv  = params + 2 * N,  *prad = params + 4 * N;
    float* phA = params + 6 * N,   *phC = params + 8 * N,  *pnB  = params + 10 * N;
    float* pop = params + 12 * N;
    float* rec   = (float*)alloc((size_t)2 * N * 24 * 4);
    float* part  = (float*)alloc((size_t)2 * NC * 18 * P_PIX * 4);
    float* tpref = (float*)alloc((size_t)2 * NC * P_PIX * 4);
    float* fmap  = (float*)alloc((size_t)2 * 17 * P_PIX * 4);
    float* sed   = (float*)alloc((size_t)2 * P_PIX * 17 * 4);
    float* ldf   = (float*)alloc((size_t)2 * 17 * 4096 * 4);
    float* proto = (float*)alloc((size_t)2 * 16 * 17 * 4);

    init_kernel<<<(2 * N + 255) / 256, 256, 0, stream>>>(rnk, out, 2 * N);
    dim3 gprep((N + 255) / 256, 2);
    prep_kernel<<<gprep, 256, 0, stream>>>(pc_xyz, scales, rots, opacity, viewmat, intrins,
                                           keys, pu, pv, prad, phA, phC, pnB, pop, N);
    dim3 grank((N + 255) / 256, (N + RANK_CHUNK - 1) / RANK_CHUNK, 2);
    rank_kernel<<<grank, 256, 0, stream>>>(keys, rnk, N);
    scatter_kernel<<<gprep, 256, 0, stream>>>(rnk, pu, pv, prad, phA, phC, pnB, pop,
                                              voxel_feats, rec, N);
    dim3 gsplat(P_PIX / 256, NC, 2);
    splat_kernel<<<gsplat, 256, 0, stream>>>(rec, part, N);
    dim3 gtp(P_PIX / 256, 2);
    tpref_kernel<<<gtp, 256, 0, stream>>>(part, tpref);
    combine_kernel<<<(2 * 17 * P_PIX + 255) / 256, 256, 0, stream>>>(part, tpref, fmap);
    mlp_kernel<<<208, 256, 0, stream>>>(sam_embd, sam_features, W1, b1, g1, be1,
                                        W2, b2, g2, be2, W3, b3, sed, ldf);
    dim3 gproto(16, 2);
    proto_kernel<<<gproto, 256, 0, stream>>>(sam_masks, ldf, proto);
    bce_kernel<<<(2 * 16 * P_PIX) / 256, 256, 0, stream>>>(sam_masks, proto, fmap, out);
    l1_kernel<<<(2 * P_PIX + 255) / 256, 256, 0, stream>>>(fmap, sed, out);
}

// Round 3
// 277.783 us; speedup vs baseline: 1.3246x; 1.3246x over previous
//
#include <hip/hip_runtime.h>
#include <math.h>

#define NPTS   12800
#define P_PIX  2560
#define NC     64          // compositing chunks (NPTS/NC = 200 pts/chunk)
#define CHUNK  200
#define RANK_CHUNK 800
#define MLP_PITCH 264      // ushorts per LDS row (256 + 8 pad)

typedef short short8 __attribute__((ext_vector_type(8)));
typedef float f32x4 __attribute__((ext_vector_type(4)));

__device__ __forceinline__ unsigned short f2bf(float f) {
    unsigned int u = __float_as_uint(f);
    u += 0x7fffu + ((u >> 16) & 1u);   // RNE
    return (unsigned short)(u >> 16);
}

// ---------------------------------------------------------------- init
__global__ __launch_bounds__(256) void init_kernel(int* rnk, float* out, int n) {
    int i = blockIdx.x * 256 + threadIdx.x;
    if (i < n) rnk[i] = 0;
    if (i == 0) out[0] = 0.0f;
}

// ---------------------------------------------------------------- per-point projection
__global__ __launch_bounds__(256) void prep_kernel(
    const float* __restrict__ xyz, const float* __restrict__ scales,
    const float* __restrict__ rots, const float* __restrict__ opacity,
    const float* __restrict__ viewmat, const float* __restrict__ intrins,
    unsigned long long* __restrict__ keys,
    float* __restrict__ pu, float* __restrict__ pv, float* __restrict__ prad,
    float* __restrict__ phA, float* __restrict__ phC, float* __restrict__ pnB,
    float* __restrict__ pop, int N) {
    int cam = blockIdx.y;
    int i = blockIdx.x * 256 + threadIdx.x;
    if (i >= N) return;
    const float* vm = viewmat + cam * 16;
    const float* it = intrins + cam * 4;
    float fx = it[0], fy = it[1], cx = it[2], cy = it[3];
    float R00 = vm[0], R01 = vm[1], R02 = vm[2], t0 = vm[3];
    float R10 = vm[4], R11 = vm[5], R12 = vm[6], t1 = vm[7];
    float R20 = vm[8], R21 = vm[9], R22 = vm[10], t2 = vm[11];
    float X = xyz[i * 3], Y = xyz[i * 3 + 1], Z = xyz[i * 3 + 2];
    float x = R00 * X + R01 * Y + R02 * Z + t0;
    float y = R10 * X + R11 * Y + R12 * Z + t1;
    float z = R20 * X + R21 * Y + R22 * Z + t2;
    float zc = fmaxf(z, 0.001f);
    float iz = 1.0f / zc;
    float u = fx * x * iz + cx;
    float v = fy * y * iz + cy;
    float qw = rots[i * 4], qx = rots[i * 4 + 1], qy = rots[i * 4 + 2], qz = rots[i * 4 + 3];
    float qn = 1.0f / sqrtf(qw * qw + qx * qx + qy * qy + qz * qz);
    qw *= qn; qx *= qn; qy *= qn; qz *= qn;
    float s0 = expf(scales[i * 3]), s1 = expf(scales[i * 3 + 1]), s2 = expf(scales[i * 3 + 2]);
    float Rq[3][3] = {
        {1 - 2 * (qy * qy + qz * qz), 2 * (qx * qy - qw * qz), 2 * (qx * qz + qw * qy)},
        {2 * (qx * qy + qw * qz), 1 - 2 * (qx * qx + qz * qz), 2 * (qy * qz - qw * qx)},
        {2 * (qx * qz - qw * qy), 2 * (qy * qz + qw * qx), 1 - 2 * (qx * qx + qy * qy)}};
    float M[3][3];
    #pragma unroll
    for (int r = 0; r < 3; ++r) { M[r][0] = Rq[r][0] * s0; M[r][1] = Rq[r][1] * s1; M[r][2] = Rq[r][2] * s2; }
    float c3[3][3];
    #pragma unroll
    for (int a = 0; a < 3; ++a)
        #pragma unroll
        for (int b = 0; b < 3; ++b)
            c3[a][b] = M[a][0] * M[b][0] + M[a][1] * M[b][1] + M[a][2] * M[b][2];
    float Rw[3][3] = {{R00, R01, R02}, {R10, R11, R12}, {R20, R21, R22}};
    float Wt[3][3];
    #pragma unroll
    for (int a = 0; a < 3; ++a)
        #pragma unroll
        for (int b = 0; b < 3; ++b)
            Wt[a][b] = Rw[a][0] * c3[0][b] + Rw[a][1] * c3[1][b] + Rw[a][2] * c3[2][b];
    float cw[3][3];
    #pragma unroll
    for (int a = 0; a < 3; ++a)
        #pragma unroll
        for (int b = 0; b < 3; ++b)
            cw[a][b] = Wt[a][0] * Rw[b][0] + Wt[a][1] * Rw[b][1] + Wt[a][2] * Rw[b][2];
    float j00 = fx * iz, j02 = -fx * x * iz * iz;
    float j11 = fy * iz, j12 = -fy * y * iz * iz;
    float c00 = j00 * j00 * cw[0][0] + 2.0f * j00 * j02 * cw[0][2] + j02 * j02 * cw[2][2];
    float c01 = j00 * j11 * cw[0][1] + j00 * j12 * cw[0][2] + j02 * j11 * cw[2][1] + j02 * j12 * cw[2][2];
    float c11 = j11 * j11 * cw[1][1] + 2.0f * j11 * j12 * cw[1][2] + j12 * j12 * cw[2][2];
    float a = c00 + 0.3f, bq = c01, cc = c11 + 0.3f;
    float det = a * cc - bq * bq;
    float A = cc / det, Bc = -bq / det, Cc = a / det;
    // conservative cull radius: Q >= 0.5*lmin*r^2, drop alpha < 1e-8
    float lmin = 0.5f * ((A + Cc) - sqrtf((A - Cc) * (A - Cc) + 4.0f * Bc * Bc));
    lmin = fmaxf(lmin, 1e-20f);
    float opv = (z > 0.2f) ? opacity[i] : 0.0f;
    float rad = -1.0f;
    if (opv > 0.0f) {
        float tcut = logf(opv) + 18.42f;  // ln(op * 1e8)
        if (tcut > 0.0f) rad = sqrtf(2.0f * tcut / lmin);
    }
    int idx = cam * N + i;
    pu[idx] = u; pv[idx] = v; prad[idx] = rad;
    phA[idx] = -0.5f * A; phC[idx] = -0.5f * Cc; pnB[idx] = -Bc;
    pop[idx] = opv;
    unsigned int zb = __float_as_uint(z);
    zb = (zb & 0x80000000u) ? ~zb : (zb | 0x80000000u);
    keys[idx] = ((unsigned long long)zb << 32) | (unsigned int)i;
}

// ---------------------------------------------------------------- stable rank
__global__ __launch_bounds__(256) void rank_kernel(const unsigned long long* __restrict__ keys,
                                                   int* __restrict__ rnk, int N) {
    __shared__ unsigned long long sk[RANK_CHUNK];
    int cam = blockIdx.z;
    const unsigned long long* K = keys + (size_t)cam * N;
    int jbase = blockIdx.y * RANK_CHUNK;
    int jcnt = min(RANK_CHUNK, N - jbase);
    for (int t = threadIdx.x; t < jcnt; t += 256) sk[t] = K[jbase + t];
    __syncthreads();
    int i = blockIdx.x * 256 + threadIdx.x;
    if (i >= N) return;
    unsigned long long ki = K[i];
    int cnt = 0;
    #pragma unroll 8
    for (int j = 0; j < jcnt; ++j) cnt += (sk[j] < ki) ? 1 : 0;
    if (cnt) atomicAdd(rnk + (size_t)cam * N + i, cnt);
}

// ---------------------------------------------------------------- scatter into sorted records
// layout: [u, v, rad, op | hA, hC, nB, f0 | f1..f16] = 24 floats
__global__ __launch_bounds__(256) void scatter_kernel(
    const int* __restrict__ rnk,
    const float* __restrict__ pu, const float* __restrict__ pv, const float* __restrict__ prad,
    const float* __restrict__ phA, const float* __restrict__ phC, const float* __restrict__ pnB,
    const float* __restrict__ pop,
    const float* __restrict__ feats, float* __restrict__ rec, int N) {
    int cam = blockIdx.y;
    int i = blockIdx.x * 256 + threadIdx.x;
    if (i >= N) return;
    int idx = cam * N + i;
    int r = rnk[idx];
    float* d = rec + ((size_t)cam * N + r) * 24;
    d[0] = pu[idx]; d[1] = pv[idx]; d[2] = prad[idx]; d[3] = pop[idx];
    d[4] = phA[idx]; d[5] = phC[idx]; d[6] = pnB[idx];
    const float* f = feats + (size_t)i * 17;
    #pragma unroll
    for (int c = 0; c < 17; ++c) d[7 + c] = f[c];
}

// ---------------------------------------------------------------- chunked alpha compositing
// LDS-staged, header/body split, band cull, 2 rows per lane
__global__ __launch_bounds__(256) void splat_kernel(const float* __restrict__ rec,
                                                    float* __restrict__ part, int N) {
    __shared__ __align__(16) float4 sHdr[CHUNK];       // u, v, rad, op
    __shared__ __align__(16) float4 sBody[CHUNK * 5];  // hA,hC,nB,f0 | f1..f16
    int cam = blockIdx.z, ch = blockIdx.y, pg = blockIdx.x;  // pg: 0..4 (8 rows each)
    int tid = threadIdx.x;
    const float4* src = (const float4*)(rec + ((size_t)cam * N + ch * CHUNK) * 24);
    for (int t = tid; t < CHUNK * 6; t += 256) {
        float4 v = src[t];
        int n = t / 6, q = t - n * 6;
        if (q == 0) sHdr[n] = v;
        else        sBody[n * 5 + q - 1] = v;
    }
    __syncthreads();
    int lane = tid & 63, wv = tid >> 6;
    int row0 = pg * 8 + wv * 2;
    float px = (float)lane;
    float py0 = (float)row0;
    float T0 = 1.0f, T1 = 1.0f;
    float acc0[17], acc1[17];
    #pragma unroll
    for (int c = 0; c < 17; ++c) { acc0[c] = 0.0f; acc1[c] = 0.0f; }
    for (int n = 0; n < CHUNK; ++n) {
        float4 hd = sHdr[n];
        float dy0 = hd.y - py0;
        float dy1 = dy0 - 1.0f;
        float dmin = fminf(fabsf(dy0), fabsf(dy1));
        if (dmin > hd.z + 0.01f) continue;   // exec-coherent skip (alpha < 1e-8)
        float4 b0 = sBody[n * 5 + 0];
        float4 b1 = sBody[n * 5 + 1];
        float4 b2 = sBody[n * 5 + 2];
        float4 b3 = sBody[n * 5 + 3];
        float4 b4 = sBody[n * 5 + 4];
        float dx = hd.x - px;
        float hAdx2 = (b0.x * dx) * dx;
        float nBdx = b0.z * dx;
        float pw0 = fmaf(b0.y * dy0, dy0, hAdx2);
        pw0 = fminf(fmaf(nBdx, dy0, pw0), 0.0f);
        float pw1 = fmaf(b0.y * dy1, dy1, hAdx2);
        pw1 = fminf(fmaf(nBdx, dy1, pw1), 0.0f);
        float al0 = fminf(0.99f, hd.w * __expf(pw0));
        float al1 = fminf(0.99f, hd.w * __expf(pw1));
        float w0 = al0 * T0, w1 = al1 * T1;
        acc0[0]  = fmaf(w0, b0.w, acc0[0]);  acc1[0]  = fmaf(w1, b0.w, acc1[0]);
        acc0[1]  = fmaf(w0, b1.x, acc0[1]);  acc1[1]  = fmaf(w1, b1.x, acc1[1]);
        acc0[2]  = fmaf(w0, b1.y, acc0[2]);  acc1[2]  = fmaf(w1, b1.y, acc1[2]);
        acc0[3]  = fmaf(w0, b1.z, acc0[3]);  acc1[3]  = fmaf(w1, b1.z, acc1[3]);
        acc0[4]  = fmaf(w0, b1.w, acc0[4]);  acc1[4]  = fmaf(w1, b1.w, acc1[4]);
        acc0[5]  = fmaf(w0, b2.x, acc0[5]);  acc1[5]  = fmaf(w1, b2.x, acc1[5]);
        acc0[6]  = fmaf(w0, b2.y, acc0[6]);  acc1[6]  = fmaf(w1, b2.y, acc1[6]);
        acc0[7]  = fmaf(w0, b2.z, acc0[7]);  acc1[7]  = fmaf(w1, b2.z, acc1[7]);
        acc0[8]  = fmaf(w0, b2.w, acc0[8]);  acc1[8]  = fmaf(w1, b2.w, acc1[8]);
        acc0[9]  = fmaf(w0, b3.x, acc0[9]);  acc1[9]  = fmaf(w1, b3.x, acc1[9]);
        acc0[10] = fmaf(w0, b3.y, acc0[10]); acc1[10] = fmaf(w1, b3.y, acc1[10]);
        acc0[11] = fmaf(w0, b3.z, acc0[11]); acc1[11] = fmaf(w1, b3.z, acc1[11]);
        acc0[12] = fmaf(w0, b3.w, acc0[12]); acc1[12] = fmaf(w1, b3.w, acc1[12]);
        acc0[13] = fmaf(w0, b4.x, acc0[13]); acc1[13] = fmaf(w1, b4.x, acc1[13]);
        acc0[14] = fmaf(w0, b4.y, acc0[14]); acc1[14] = fmaf(w1, b4.y, acc1[14]);
        acc0[15] = fmaf(w0, b4.z, acc0[15]); acc1[15] = fmaf(w1, b4.z, acc1[15]);
        acc0[16] = fmaf(w0, b4.w, acc0[16]); acc1[16] = fmaf(w1, b4.w, acc1[16]);
        T0 *= (1.0f - al0);
        T1 *= (1.0f - al1);
    }
    int p0 = row0 * 64 + lane;
    size_t base = ((size_t)(cam * NC + ch) * 18) * P_PIX;
    part[base + p0] = T0;
    part[base + p0 + 64] = T1;
    #pragma unroll
    for (int c = 0; c < 17; ++c) {
        part[base + (size_t)(1 + c) * P_PIX + p0] = acc0[c];
        part[base + (size_t)(1 + c) * P_PIX + p0 + 64] = acc1[c];
    }
}

// ---------------------------------------------------------------- per-pixel transmittance prefix
__global__ __launch_bounds__(256) void tpref_kernel(const float* __restrict__ part,
                                                    float* __restrict__ tpref) {
    int cam = blockIdx.y;
    int p = blockIdx.x * 256 + threadIdx.x;
    float T = 1.0f;
    #pragma unroll 8
    for (int k = 0; k < NC; ++k) {
        tpref[((size_t)(cam * NC + k)) * P_PIX + p] = T;
        T *= part[((size_t)(cam * NC + k) * 18) * P_PIX + p];
    }
}

// ---------------------------------------------------------------- combine chunks -> fmap
__global__ __launch_bounds__(256) void combine_kernel(const float* __restrict__ part,
                                                      const float* __restrict__ tpref,
                                                      float* __restrict__ fmap) {
    int idx = blockIdx.x * 256 + threadIdx.x;
    if (idx >= 2 * 17 * P_PIX) return;
    int p = idx % P_PIX;
    int rem = idx / P_PIX;
    int c = rem % 17;
    int cam = rem / 17;
    float acc = 0.0f;
    #pragma unroll 8
    for (int k = 0; k < NC; ++k) {
        float Tp = tpref[((size_t)(cam * NC + k)) * P_PIX + p];
        float S = part[(((size_t)(cam * NC + k)) * 18 + 1 + c) * P_PIX + p];
        acc = fmaf(Tp, S, acc);
    }
    fmap[((size_t)cam * 17 + c) * P_PIX + p] = acc;
}

// ---------------------------------------------------------------- MLP: bf16 MFMA layer1 + fp32 L2/L3
__global__ __launch_bounds__(256, 1) void mlp_kernel(
    const float* __restrict__ embd, const float* __restrict__ sfeat,
    const float* __restrict__ W1, const float* __restrict__ b1,
    const float* __restrict__ g1, const float* __restrict__ be1,
    const float* __restrict__ W2, const float* __restrict__ b2,
    const float* __restrict__ g2, const float* __restrict__ be2,
    const float* __restrict__ W3, const float* __restrict__ b3,
    float* __restrict__ sed, float* __restrict__ ldf) {
    __shared__ unsigned short sX[64 * MLP_PITCH];   // [row][k] bf16, A-layout
    __shared__ unsigned short sW[64 * MLP_PITCH];   // [n][k]  bf16, B-layout (W1 as-is)
    __shared__ float sH[4][16 * 65];                // per-wave h (post-bias, pre-LN)
    int tid = threadIdx.x;
    int tile = blockIdx.x;
    const float* xbase;
    if (tile < 80) {           // sed tiles: 64 consecutive pixels, one source row ri
        int cam = tile / 40; int r = tile % 40;
        int ri = (r * 8) / 5;  // floor(r*64/40)
        xbase = embd + (size_t)cam * 256 * 4096 + ri * 64;
    } else {                   // ldf tiles: 64 consecutive t
        int tt = tile - 80; int cam = tt >> 6;
        xbase = sfeat + (size_t)cam * 256 * 4096 + (tt & 63) * 64;
    }
    const float4* xf4 = (const float4*)xbase;
    for (int idx = tid; idx < 4096; idx += 256) {
        int k = idx >> 4, q = idx & 15;
        float4 xv = xf4[(size_t)k * 1024 + q];
        int r = q * 4;
        sX[(r + 0) * MLP_PITCH + k] = f2bf(xv.x);
        sX[(r + 1) * MLP_PITCH + k] = f2bf(xv.y);
        sX[(r + 2) * MLP_PITCH + k] = f2bf(xv.z);
        sX[(r + 3) * MLP_PITCH + k] = f2bf(xv.w);
    }
    const float4* wf4 = (const float4*)W1;
    for (int idx = tid; idx < 4096; idx += 256) {
        float4 wv = wf4[idx];
        int n = idx >> 6, kq = (idx & 63) * 4;
        uint2 pk;
        pk.x = (unsigned int)f2bf(wv.x) | ((unsigned int)f2bf(wv.y) << 16);
        pk.y = (unsigned int)f2bf(wv.z) | ((unsigned int)f2bf(wv.w) << 16);
        *(uint2*)&sW[n * MLP_PITCH + kq] = pk;
    }
    int lane = tid & 63, wv_ = tid >> 6;
    int c17 = lane < 17 ? lane : 16;
    float w2c[64], w3c[64];
    #pragma unroll
    for (int k = 0; k < 64; ++k) w2c[k] = W2[lane * 64 + k];
    #pragma unroll
    for (int k = 0; k < 64; ++k) w3c[k] = W3[c17 * 64 + k];
    float g1l = g1[lane], be1l = be1[lane];
    float b2l = b2[lane], g2l = g2[lane], be2l = be2[lane];
    float b3l = b3[c17];
    __syncthreads();
    int rbase = wv_ * 16;
    int m = lane & 15, kq4 = lane >> 4;
    f32x4 acc[4];
    #pragma unroll
    for (int nt = 0; nt < 4; ++nt) acc[nt] = (f32x4){0.f, 0.f, 0.f, 0.f};
    const unsigned short* aptr = sX + (rbase + m) * MLP_PITCH + kq4 * 8;
    const unsigned short* bptr = sW + m * MLP_PITCH + kq4 * 8;
    #pragma unroll
    for (int ks = 0; ks < 8; ++ks) {
        short8 af = *(const short8*)(aptr + ks * 32);
        #pragma unroll
        for (int nt = 0; nt < 4; ++nt) {
            short8 bf = *(const short8*)(bptr + nt * 16 * MLP_PITCH + ks * 32);
            acc[nt] = __builtin_amdgcn_mfma_f32_16x16x32_bf16(af, bf, acc[nt], 0, 0, 0);
        }
    }
    int q4 = kq4 * 4;
    #pragma unroll
    for (int nt = 0; nt < 4; ++nt) {
        float bv = b1[nt * 16 + m];
        #pragma unroll
        for (int rg = 0; rg < 4; ++rg)
            sH[wv_][(q4 + rg) * 65 + nt * 16 + m] = acc[nt][rg] + bv;
    }
    for (int r = 0; r < 16; ++r) {
        float h = sH[wv_][r * 65 + lane];
        float s = h;
        #pragma unroll
        for (int o = 32; o; o >>= 1) s += __shfl_xor(s, o);
        float mu = s * (1.0f / 64.0f);
        float d = h - mu;
        float vs = d * d;
        #pragma unroll
        for (int o = 32; o; o >>= 1) vs += __shfl_xor(vs, o);
        float hn = d * (1.0f / sqrtf(vs * (1.0f / 64.0f) + 1e-5f)) * g1l + be1l;
        hn = fmaxf(hn, 0.01f * hn);
        float a2 = 0.0f;
        #pragma unroll
        for (int k = 0; k < 64; ++k) a2 = fmaf(__shfl(hn, k), w2c[k], a2);
        float h2 = a2 + b2l;
        s = h2;
        #pragma unroll
        for (int o = 32; o; o >>= 1) s += __shfl_xor(s, o);
        float mu2 = s * (1.0f / 64.0f);
        float d2 = h2 - mu2;
        float vs2 = d2 * d2;
        #pragma unroll
        for (int o = 32; o; o >>= 1) vs2 += __shfl_xor(vs2, o);
        float hn2 = d2 * (1.0f / sqrtf(vs2 * (1.0f / 64.0f) + 1e-5f)) * g2l + be2l;
        hn2 = fmaxf(hn2, 0.01f * hn2);
        float a3 = 0.0f;
        #pragma unroll
        for (int k = 0; k < 64; ++k) a3 = fmaf(__shfl(hn2, k), w3c[k], a3);
        float outv = a3 + b3l;
        if (lane < 17) {
            int row = tile * 64 + rbase + r;
            if (row < 5120) {
                int cam = row / 2560; int p = row - cam * 2560;
                sed[((size_t)cam * 2560 + p) * 17 + lane] = outv;
            } else {
                int rr = row - 5120; int cam = rr >> 12; int t = rr & 4095;
                ldf[((size_t)cam * 17 + lane) * 4096 + t] = outv;
            }
        }
    }
}

// ---------------------------------------------------------------- mask prototypes
__global__ __launch_bounds__(256) void proto_kernel(const float* __restrict__ masks,
                                                    const float* __restrict__ ldf,
                                                    float* __restrict__ proto) {
    int cam = blockIdx.y, m = blockIdx.x;
    const float* M = masks + ((size_t)cam * 16 + m) * 40000;
    float acc[18];
    #pragma unroll
    for (int j = 0; j < 18; ++j) acc[j] = 0.0f;
    for (int t = threadIdx.x; t < 4096; t += 256) {
        int h = t >> 6, w = t & 63;
        int rh = (h * 25) >> 3, rw = (w * 25) >> 3;
        float lv = M[rh * 200 + rw];
        if (lv != 0.0f) {
            acc[17] += lv;
            const float* L = ldf + (size_t)cam * 17 * 4096 + t;
            #pragma unroll
            for (int c = 0; c < 17; ++c) acc[c] = fmaf(lv, L[(size_t)c * 4096], acc[c]);
        }
    }
    __shared__ float red[4][18];
    int lane = threadIdx.x & 63, wv = threadIdx.x >> 6;
    #pragma unroll
    for (int j = 0; j < 18; ++j) {
        float v = acc[j];
        #pragma unroll
        for (int o = 32; o; o >>= 1) v += __shfl_xor(v, o);
        if (lane == 0) red[wv][j] = v;
    }
    __syncthreads();
    if (threadIdx.x < 17) {
        float sacc = red[0][threadIdx.x] + red[1][threadIdx.x] + red[2][threadIdx.x] + red[3][threadIdx.x];
        float ms = red[0][17] + red[1][17] + red[2][17] + red[3][17];
        proto[((size_t)cam * 16 + m) * 17 + threadIdx.x] = sacc / fmaxf(ms, 1e-6f);
    }
}

__device__ __forceinline__ void block_atomic_add(float v, float* target) {
    #pragma unroll
    for (int o = 32; o; o >>= 1) v += __shfl_xor(v, o);
    __shared__ float sred[4];
    int lane = threadIdx.x & 63, wv = threadIdx.x >> 6;
    if (lane == 0) sred[wv] = v;
    __syncthreads();
    if (threadIdx.x == 0) atomicAdd(target, sred[0] + sred[1] + sred[2] + sred[3]);
}

// ---------------------------------------------------------------- BCE loss
__global__ __launch_bounds__(256) void bce_kernel(const float* __restrict__ masks,
                                                  const float* __restrict__ proto,
                                                  const float* __restrict__ fmap,
                                                  float* __restrict__ out) {
    int idx = blockIdx.x * 256 + threadIdx.x;
    int p = idx % P_PIX;
    int rem = idx / P_PIX;
    int m = rem & 15, cam = rem >> 4;
    const float* pr = proto + ((size_t)cam * 16 + m) * 17;
    float sdot = 0;
    #pragma unroll
    for (int c = 0; c < 17; ++c)
        sdot = fmaf(pr[c], fmap[((size_t)cam * 17 + c) * P_PIX + p], sdot);
    float prob = 1.0f / (1.0f + expf(-sdot));
    int px = p & 63, py = p >> 6;
    float src_r = (py + 0.5f) * 5.0f - 0.5f;
    float src_c = (px + 0.5f) * 3.125f - 0.5f;
    int r0 = (int)fminf(fmaxf(floorf(src_r), 0.0f), 199.0f);
    int r1 = min(r0 + 1, 199);
    float wr = fminf(fmaxf(src_r - (float)r0, 0.0f), 1.0f);
    int c0 = (int)fminf(fmaxf(floorf(src_c), 0.0f), 199.0f);
    int c1 = min(c0 + 1, 199);
    float wc = fminf(fmaxf(src_c - (float)c0, 0.0f), 1.0f);
    const float* M = masks + ((size_t)cam * 16 + m) * 40000;
    float v00 = M[r0 * 200 + c0], v01 = M[r0 * 200 + c1];
    float v10 = M[r1 * 200 + c0], v11 = M[r1 * 200 + c1];
    float xr0 = v00 * (1.0f - wr) + v10 * wr;
    float xr1 = v01 * (1.0f - wr) + v11 * wr;
    float frm = xr0 * (1.0f - wc) + xr1 * wc;
    frm = (frm <= 0.5f) ? 0.0f : frm;
    float bce = frm * logf(prob + 1e-8f) + (1.0f - frm) * logf(1.0f - prob + 1e-8f);
    block_atomic_add(bce * (-1.0f / (16.0f * 2560.0f * 2.0f)), out);
}

// ---------------------------------------------------------------- L1 loss
__global__ __launch_bounds__(256) void l1_kernel(const float* __restrict__ fmap,
                                                 const float* __restrict__ sed,
                                                 float* __restrict__ out) {
    int idx = blockIdx.x * 256 + threadIdx.x;
    float ssum = 0;
    if (idx < 2 * P_PIX) {
        int p = idx % P_PIX, cam = idx / P_PIX;
        #pragma unroll
        for (int c = 0; c < 17; ++c) {
            float dv = fmap[((size_t)cam * 17 + c) * P_PIX + p] - sed[((size_t)cam * P_PIX + p) * 17 + c];
            ssum += fabsf(dv);
        }
    }
    block_atomic_add(ssum * (1.0f / (43520.0f * 2.0f)), out);
}

// ================================================================ launch
extern "C" void kernel_launch(void* const* d_in, const int* in_sizes, int n_in,
                              void* d_out, int out_size, void* d_ws, size_t ws_size,
                              hipStream_t stream) {
    const float* voxel_feats = (const float*)d_in[0];
    const float* opacity     = (const float*)d_in[1];
    const float* sam_embd    = (const float*)d_in[2];
    const float* sam_features= (const float*)d_in[3];
    const float* sam_masks   = (const float*)d_in[4];
    const float* viewmat     = (const float*)d_in[5];
    const float* intrins     = (const float*)d_in[6];
    const float* pc_xyz      = (const float*)d_in[7];
    const float* scales      = (const float*)d_in[8];
    const float* rots        = (const float*)d_in[9];
    const float* W1 = (const float*)d_in[10], *b1 = (const float*)d_in[11];
    const float* g1 = (const float*)d_in[12], *be1 = (const float*)d_in[13];
    const float* W2 = (const float*)d_in[14], *b2 = (const float*)d_in[15];
    const float* g2 = (const float*)d_in[16], *be2 = (const float*)d_in[17];
    const float* W3 = (const float*)d_in[18], *b3 = (const float*)d_in[19];
    float* out = (float*)d_out;
    const int N = in_sizes[7] / 3;  // 12800

    char* w = (char*)d_ws;
    size_t off = 0;
    auto alloc = [&](size_t bytes) -> void* {
        off = (off + 255) & ~(size_t)255;
        void* p = w + off; off += bytes; return p;
    };
    int* rnk  = (int*)alloc((size_t)2 * N * sizeof(int));
    unsigned long long* keys = (unsigned long long*)alloc((size_t)2 * N * 8);
    float* params = (float*)alloc((size_t)7 * 2 * N * 4);
    float* pu  = params,           *pv  = params + 2 * N,  *prad = params + 4 * N;
    float* phA = params + 6 * N,   *phC = params + 8 * N,  *pnB  = params + 10 * N;
    float* pop = params + 12 * N;
    float* rec   = (float*)alloc((size_t)2 * N * 24 * 4);
    float* part  = (float*)alloc((size_t)2 * NC * 18 * P_PIX * 4);
    float* tpref = (float*)alloc((size_t)2 * NC * P_PIX * 4);
    float* fmap  = (float*)alloc((size_t)2 * 17 * P_PIX * 4);
    float* sed   = (float*)alloc((size_t)2 * P_PIX * 17 * 4);
    float* ldf   = (float*)alloc((size_t)2 * 17 * 4096 * 4);
    float* proto = (float*)alloc((size_t)2 * 16 * 17 * 4);

    init_kernel<<<(2 * N + 255) / 256, 256, 0, stream>>>(rnk, out, 2 * N);
    dim3 gprep((N + 255) / 256, 2);
    prep_kernel<<<gprep, 256, 0, stream>>>(pc_xyz, scales, rots, opacity, viewmat, intrins,
                                           keys, pu, pv, prad, phA, phC, pnB, pop, N);
    dim3 grank((N + 255) / 256, (N + RANK_CHUNK - 1) / RANK_CHUNK, 2);
    rank_kernel<<<grank, 256, 0, stream>>>(keys, rnk, N);
    scatter_kernel<<<gprep, 256, 0, stream>>>(rnk, pu, pv, prad, phA, phC, pnB, pop,
                                              voxel_feats, rec, N);
    dim3 gsplat(5, NC, 2);   // 5 row-groups x 64 chunks x 2 cams
    splat_kernel<<<gsplat, 256, 0, stream>>>(rec, part, N);
    dim3 gtp(P_PIX / 256, 2);
    tpref_kernel<<<gtp, 256, 0, stream>>>(part, tpref);
    combine_kernel<<<(2 * 17 * P_PIX + 255) / 256, 256, 0, stream>>>(part, tpref, fmap);
    mlp_kernel<<<208, 256, 0, stream>>>(sam_embd, sam_features, W1, b1, g1, be1,
                                        W2, b2, g2, be2, W3, b3, sed, ldf);
    dim3 gproto(16, 2);
    proto_kernel<<<gproto, 256, 0, stream>>>(sam_masks, ldf, proto);
    bce_kernel<<<(2 * 16 * P_PIX) / 256, 256, 0, stream>>>(sam_masks, proto, fmap, out);
    l1_kernel<<<(2 * P_PIX + 255) / 256, 256, 0, stream>>>(fmap, sed, out);
}

// Round 4
// 236.290 us; speedup vs baseline: 1.5572x; 1.1756x over previous
//
#include <hip/hip_runtime.h>
#include <math.h>

#define NPTS   12800
#define P_PIX  2560
#define NC     64          // compositing chunks (NPTS/NC = 200 pts/chunk)
#define CHUNK  200
#define RANK_CHUNK 800
#define MLP_PITCH 264      // ushorts per LDS row (256 + 8 pad)

typedef short short8 __attribute__((ext_vector_type(8)));
typedef float f32x4 __attribute__((ext_vector_type(4)));

__device__ __forceinline__ unsigned short f2bf(float f) {
    unsigned int u = __float_as_uint(f);
    u += 0x7fffu + ((u >> 16) & 1u);   // RNE
    return (unsigned short)(u >> 16);
}

// ---------------------------------------------------------------- init
__global__ __launch_bounds__(256) void init_kernel(int* rnk, float* out, int n) {
    int i = blockIdx.x * 256 + threadIdx.x;
    if (i < n) rnk[i] = 0;
    if (i == 0) out[0] = 0.0f;
}

// ---------------------------------------------------------------- per-point projection
__global__ __launch_bounds__(256) void prep_kernel(
    const float* __restrict__ xyz, const float* __restrict__ scales,
    const float* __restrict__ rots, const float* __restrict__ opacity,
    const float* __restrict__ viewmat, const float* __restrict__ intrins,
    unsigned long long* __restrict__ keys,
    float* __restrict__ pu, float* __restrict__ pv, float* __restrict__ prad,
    float* __restrict__ phA, float* __restrict__ phC, float* __restrict__ pnB,
    float* __restrict__ pop, int N) {
    int cam = blockIdx.y;
    int i = blockIdx.x * 256 + threadIdx.x;
    if (i >= N) return;
    const float* vm = viewmat + cam * 16;
    const float* it = intrins + cam * 4;
    float fx = it[0], fy = it[1], cx = it[2], cy = it[3];
    float R00 = vm[0], R01 = vm[1], R02 = vm[2], t0 = vm[3];
    float R10 = vm[4], R11 = vm[5], R12 = vm[6], t1 = vm[7];
    float R20 = vm[8], R21 = vm[9], R22 = vm[10], t2 = vm[11];
    float X = xyz[i * 3], Y = xyz[i * 3 + 1], Z = xyz[i * 3 + 2];
    float x = R00 * X + R01 * Y + R02 * Z + t0;
    float y = R10 * X + R11 * Y + R12 * Z + t1;
    float z = R20 * X + R21 * Y + R22 * Z + t2;
    float zc = fmaxf(z, 0.001f);
    float iz = 1.0f / zc;
    float u = fx * x * iz + cx;
    float v = fy * y * iz + cy;
    float qw = rots[i * 4], qx = rots[i * 4 + 1], qy = rots[i * 4 + 2], qz = rots[i * 4 + 3];
    float qn = 1.0f / sqrtf(qw * qw + qx * qx + qy * qy + qz * qz);
    qw *= qn; qx *= qn; qy *= qn; qz *= qn;
    float s0 = expf(scales[i * 3]), s1 = expf(scales[i * 3 + 1]), s2 = expf(scales[i * 3 + 2]);
    float Rq[3][3] = {
        {1 - 2 * (qy * qy + qz * qz), 2 * (qx * qy - qw * qz), 2 * (qx * qz + qw * qy)},
        {2 * (qx * qy + qw * qz), 1 - 2 * (qx * qx + qz * qz), 2 * (qy * qz - qw * qx)},
        {2 * (qx * qz - qw * qy), 2 * (qy * qz + qw * qx), 1 - 2 * (qx * qx + qy * qy)}};
    float M[3][3];
    #pragma unroll
    for (int r = 0; r < 3; ++r) { M[r][0] = Rq[r][0] * s0; M[r][1] = Rq[r][1] * s1; M[r][2] = Rq[r][2] * s2; }
    float c3[3][3];
    #pragma unroll
    for (int a = 0; a < 3; ++a)
        #pragma unroll
        for (int b = 0; b < 3; ++b)
            c3[a][b] = M[a][0] * M[b][0] + M[a][1] * M[b][1] + M[a][2] * M[b][2];
    float Rw[3][3] = {{R00, R01, R02}, {R10, R11, R12}, {R20, R21, R22}};
    float Wt[3][3];
    #pragma unroll
    for (int a = 0; a < 3; ++a)
        #pragma unroll
        for (int b = 0; b < 3; ++b)
            Wt[a][b] = Rw[a][0] * c3[0][b] + Rw[a][1] * c3[1][b] + Rw[a][2] * c3[2][b];
    float cw[3][3];
    #pragma unroll
    for (int a = 0; a < 3; ++a)
        #pragma unroll
        for (int b = 0; b < 3; ++b)
            cw[a][b] = Wt[a][0] * Rw[b][0] + Wt[a][1] * Rw[b][1] + Wt[a][2] * Rw[b][2];
    float j00 = fx * iz, j02 = -fx * x * iz * iz;
    float j11 = fy * iz, j12 = -fy * y * iz * iz;
    float c00 = j00 * j00 * cw[0][0] + 2.0f * j00 * j02 * cw[0][2] + j02 * j02 * cw[2][2];
    float c01 = j00 * j11 * cw[0][1] + j00 * j12 * cw[0][2] + j02 * j11 * cw[2][1] + j02 * j12 * cw[2][2];
    float c11 = j11 * j11 * cw[1][1] + 2.0f * j11 * j12 * cw[1][2] + j12 * j12 * cw[2][2];
    float a = c00 + 0.3f, bq = c01, cc = c11 + 0.3f;
    float det = a * cc - bq * bq;
    float A = cc / det, Bc = -bq / det, Cc = a / det;
    float lmin = 0.5f * ((A + Cc) - sqrtf((A - Cc) * (A - Cc) + 4.0f * Bc * Bc));
    lmin = fmaxf(lmin, 1e-20f);
    float opv = (z > 0.2f) ? opacity[i] : 0.0f;
    float rad = -1.0f;
    if (opv > 0.0f) {
        float tcut = logf(opv) + 18.42f;  // ln(op * 1e8)
        if (tcut > 0.0f) rad = sqrtf(2.0f * tcut / lmin);
    }
    int idx = cam * N + i;
    pu[idx] = u; pv[idx] = v; prad[idx] = rad;
    phA[idx] = -0.5f * A; phC[idx] = -0.5f * Cc; pnB[idx] = -Bc;
    pop[idx] = opv;
    unsigned int zb = __float_as_uint(z);
    zb = (zb & 0x80000000u) ? ~zb : (zb | 0x80000000u);
    keys[idx] = ((unsigned long long)zb << 32) | (unsigned int)i;
}

// ---------------------------------------------------------------- stable rank
__global__ __launch_bounds__(256) void rank_kernel(const unsigned long long* __restrict__ keys,
                                                   int* __restrict__ rnk, int N) {
    __shared__ unsigned long long sk[RANK_CHUNK];
    int cam = blockIdx.z;
    const unsigned long long* K = keys + (size_t)cam * N;
    int jbase = blockIdx.y * RANK_CHUNK;
    int jcnt = min(RANK_CHUNK, N - jbase);
    for (int t = threadIdx.x; t < jcnt; t += 256) sk[t] = K[jbase + t];
    __syncthreads();
    int i = blockIdx.x * 256 + threadIdx.x;
    if (i >= N) return;
    unsigned long long ki = K[i];
    int cnt = 0;
    #pragma unroll 8
    for (int j = 0; j < jcnt; ++j) cnt += (sk[j] < ki) ? 1 : 0;
    if (cnt) atomicAdd(rnk + (size_t)cam * N + i, cnt);
}

// ---------------------------------------------------------------- scatter into sorted records
// layout: [u, v, rad, op | hA, hC, nB, f0 | f1..f16] = 24 floats
__global__ __launch_bounds__(256) void scatter_kernel(
    const int* __restrict__ rnk,
    const float* __restrict__ pu, const float* __restrict__ pv, const float* __restrict__ prad,
    const float* __restrict__ phA, const float* __restrict__ phC, const float* __restrict__ pnB,
    const float* __restrict__ pop,
    const float* __restrict__ feats, float* __restrict__ rec, int N) {
    int cam = blockIdx.y;
    int i = blockIdx.x * 256 + threadIdx.x;
    if (i >= N) return;
    int idx = cam * N + i;
    int r = rnk[idx];
    float* d = rec + ((size_t)cam * N + r) * 24;
    d[0] = pu[idx]; d[1] = pv[idx]; d[2] = prad[idx]; d[3] = pop[idx];
    d[4] = phA[idx]; d[5] = phC[idx]; d[6] = pnB[idx];
    const float* f = feats + (size_t)i * 17;
    #pragma unroll
    for (int c = 0; c < 17; ++c) d[7 + c] = f[c];
}

// ---------------------------------------------------------------- build per-(cam,chunk,row) pass lists
// one wave per list; ballot compaction preserves depth order
__global__ __launch_bounds__(256) void build_kernel(const float* __restrict__ rec,
                                                    unsigned char* __restrict__ lists,
                                                    int* __restrict__ cnts, int N) {
    int gid = blockIdx.x * 4 + (threadIdx.x >> 6);   // list id 0..5119
    int lane = threadIdx.x & 63;
    int cam = gid / (NC * 40);
    int rem = gid - cam * (NC * 40);
    int ch = rem / 40, row = rem - ch * 40;
    const float* rb = rec + ((size_t)cam * N + ch * CHUNK) * 24;
    unsigned char* L = lists + (size_t)gid * CHUNK;
    float py = (float)row;
    int cnt = 0;
    for (int g = 0; g < CHUNK; g += 64) {
        int n = g + lane;
        bool pass = false;
        if (n < CHUNK) {
            float v = rb[n * 24 + 1], rad = rb[n * 24 + 2];
            pass = fabsf(v - py) <= rad + 0.01f;
        }
        unsigned long long mask = __ballot(pass);
        int pre = __popcll(mask & ((1ull << lane) - 1ull));
        if (pass) L[cnt + pre] = (unsigned char)n;
        cnt += __popcll(mask);
    }
    if (lane == 0) cnts[gid] = cnt;
}

// ---------------------------------------------------------------- chunked alpha compositing (list-driven)
__global__ __launch_bounds__(256) void splat_kernel(const float* __restrict__ rec,
                                                    const unsigned char* __restrict__ lists,
                                                    const int* __restrict__ cnts,
                                                    float* __restrict__ part, int N) {
    __shared__ __align__(16) float4 sRec[CHUNK * 6];
    __shared__ unsigned char sList[4 * CHUNK];
    __shared__ int sCnt[4];
    int cam = blockIdx.z, ch = blockIdx.y, pg = blockIdx.x;  // pg 0..9, 4 rows per block
    int tid = threadIdx.x, lane = tid & 63, wv = tid >> 6;
    const float4* src = (const float4*)(rec + ((size_t)cam * N + ch * CHUNK) * 24);
    for (int t = tid; t < CHUNK * 6; t += 256) sRec[t] = src[t];
    int lid0 = (cam * NC + ch) * 40 + pg * 4;
    for (int t = tid; t < 4 * CHUNK; t += 256) {
        int w = t / CHUNK, i = t - w * CHUNK;
        sList[t] = lists[(size_t)(lid0 + w) * CHUNK + i];
    }
    if (tid < 4) sCnt[tid] = cnts[lid0 + tid];
    __syncthreads();
    int row = pg * 4 + wv;
    int cnt = sCnt[wv];
    float px = (float)lane, py = (float)row;
    float T = 1.0f;
    float acc[17];
    #pragma unroll
    for (int c = 0; c < 17; ++c) acc[c] = 0.0f;
    const unsigned char* myL = sList + wv * CHUNK;
    for (int i = 0; i < cnt; ++i) {
        int n = myL[i];                        // wave-uniform -> LDS broadcast
        const float4* rp = sRec + n * 6;
        float4 h  = rp[0];   // u, v, rad, op
        float4 b0 = rp[1];   // hA, hC, nB, f0
        float dy = h.y - py;
        float dx = h.x - px;
        float hCdy2 = (b0.y * dy) * dy;
        float t1 = fmaf(b0.x, dx, b0.z * dy);
        float power = fminf(fmaf(t1, dx, hCdy2), 0.0f);
        float alpha = fminf(0.99f, h.w * __expf(power));
        float w = alpha * T;
        float4 q1 = rp[2], q2 = rp[3], q3 = rp[4], q4 = rp[5];
        acc[0]  = fmaf(w, b0.w, acc[0]);
        acc[1]  = fmaf(w, q1.x, acc[1]);  acc[2]  = fmaf(w, q1.y, acc[2]);
        acc[3]  = fmaf(w, q1.z, acc[3]);  acc[4]  = fmaf(w, q1.w, acc[4]);
        acc[5]  = fmaf(w, q2.x, acc[5]);  acc[6]  = fmaf(w, q2.y, acc[6]);
        acc[7]  = fmaf(w, q2.z, acc[7]);  acc[8]  = fmaf(w, q2.w, acc[8]);
        acc[9]  = fmaf(w, q3.x, acc[9]);  acc[10] = fmaf(w, q3.y, acc[10]);
        acc[11] = fmaf(w, q3.z, acc[11]); acc[12] = fmaf(w, q3.w, acc[12]);
        acc[13] = fmaf(w, q4.x, acc[13]); acc[14] = fmaf(w, q4.y, acc[14]);
        acc[15] = fmaf(w, q4.z, acc[15]); acc[16] = fmaf(w, q4.w, acc[16]);
        T *= (1.0f - alpha);
    }
    int p0 = row * 64 + lane;
    size_t base = ((size_t)(cam * NC + ch) * 18) * P_PIX;
    part[base + p0] = T;
    #pragma unroll
    for (int c = 0; c < 17; ++c)
        part[base + (size_t)(1 + c) * P_PIX + p0] = acc[c];
}

// ---------------------------------------------------------------- per-pixel transmittance prefix
__global__ __launch_bounds__(256) void tpref_kernel(const float* __restrict__ part,
                                                    float* __restrict__ tpref) {
    int cam = blockIdx.y;
    int p = blockIdx.x * 256 + threadIdx.x;
    float T = 1.0f;
    #pragma unroll 8
    for (int k = 0; k < NC; ++k) {
        tpref[((size_t)(cam * NC + k)) * P_PIX + p] = T;
        T *= part[((size_t)(cam * NC + k) * 18) * P_PIX + p];
    }
}

// ---------------------------------------------------------------- combine chunks -> fmap
__global__ __launch_bounds__(256) void combine_kernel(const float* __restrict__ part,
                                                      const float* __restrict__ tpref,
                                                      float* __restrict__ fmap) {
    int idx = blockIdx.x * 256 + threadIdx.x;
    if (idx >= 2 * 17 * P_PIX) return;
    int p = idx % P_PIX;
    int rem = idx / P_PIX;
    int c = rem % 17;
    int cam = rem / 17;
    float acc = 0.0f;
    #pragma unroll 8
    for (int k = 0; k < NC; ++k) {
        float Tp = tpref[((size_t)(cam * NC + k)) * P_PIX + p];
        float S = part[(((size_t)(cam * NC + k)) * 18 + 1 + c) * P_PIX + p];
        acc = fmaf(Tp, S, acc);
    }
    fmap[((size_t)cam * 17 + c) * P_PIX + p] = acc;
}

// ---------------------------------------------------------------- MLP: MFMA all 3 layers
// LDS: sX(33.8K) + sW(33.8K) = 67.6 KB -> 2 blocks/CU. After L1, regions are
// aliased: hbuf/hbuf2 (per-wave 16x72 bf16) into sX, W2b/W3b into sW.
__global__ __launch_bounds__(256, 2) void mlp_kernel(
    const float* __restrict__ embd, const float* __restrict__ sfeat,
    const float* __restrict__ W1, const float* __restrict__ b1,
    const float* __restrict__ g1, const float* __restrict__ be1,
    const float* __restrict__ W2, const float* __restrict__ b2,
    const float* __restrict__ g2, const float* __restrict__ be2,
    const float* __restrict__ W3, const float* __restrict__ b3,
    float* __restrict__ sed, float* __restrict__ ldf) {
    __shared__ __align__(16) unsigned short smem[2 * 64 * MLP_PITCH];
    unsigned short* sX = smem;
    unsigned short* sW = smem + 64 * MLP_PITCH;
    int tid = threadIdx.x, lane = tid & 63, wv = tid >> 6;
    int m = lane & 15, kq = lane >> 4, q4 = kq * 4;
    int tile = blockIdx.x;
    const float* xbase;
    if (tile < 80) {
        int cam = tile / 40; int r = tile - cam * 40;
        int ri = (r * 8) / 5;  // floor(r*64/40)
        xbase = embd + (size_t)cam * 256 * 4096 + ri * 64;
    } else {
        int tt = tile - 80; int cam = tt >> 6;
        xbase = sfeat + (size_t)cam * 256 * 4096 + (tt & 63) * 64;
    }
    const float4* xf4 = (const float4*)xbase;
    for (int idx = tid; idx < 4096; idx += 256) {
        int k = idx >> 4, q = idx & 15;
        float4 xv = xf4[(size_t)k * 1024 + q];
        int r = q * 4;
        sX[(r + 0) * MLP_PITCH + k] = f2bf(xv.x);
        sX[(r + 1) * MLP_PITCH + k] = f2bf(xv.y);
        sX[(r + 2) * MLP_PITCH + k] = f2bf(xv.z);
        sX[(r + 3) * MLP_PITCH + k] = f2bf(xv.w);
    }
    const float4* wf4 = (const float4*)W1;
    for (int idx = tid; idx < 4096; idx += 256) {
        float4 wvv = wf4[idx];
        int n = idx >> 6, kk = (idx & 63) * 4;
        uint2 pk;
        pk.x = (unsigned int)f2bf(wvv.x) | ((unsigned int)f2bf(wvv.y) << 16);
        pk.y = (unsigned int)f2bf(wvv.z) | ((unsigned int)f2bf(wvv.w) << 16);
        *(uint2*)&sW[n * MLP_PITCH + kk] = pk;
    }
    // per-col params (col = nt*16 + m)
    float b1v[4], g1v[4], be1v[4], b2v[4], g2v[4], be2v[4];
    #pragma unroll
    for (int nt = 0; nt < 4; ++nt) {
        int c = nt * 16 + m;
        b1v[nt] = b1[c]; g1v[nt] = g1[c]; be1v[nt] = be1[c];
        b2v[nt] = b2[c]; g2v[nt] = g2[c]; be2v[nt] = be2[c];
    }
    __syncthreads();
    // ---- layer 1 MFMA: rows = wv*16..+15, K=256, N=64
    f32x4 acc[4];
    #pragma unroll
    for (int nt = 0; nt < 4; ++nt) acc[nt] = (f32x4){0.f, 0.f, 0.f, 0.f};
    const unsigned short* aptr = sX + (wv * 16 + m) * MLP_PITCH + kq * 8;
    const unsigned short* bptr = sW + m * MLP_PITCH + kq * 8;
    #pragma unroll
    for (int ks = 0; ks < 8; ++ks) {
        short8 af = *(const short8*)(aptr + ks * 32);
        #pragma unroll
        for (int nt = 0; nt < 4; ++nt) {
            short8 bf = *(const short8*)(bptr + nt * 16 * MLP_PITCH + ks * 32);
            acc[nt] = __builtin_amdgcn_mfma_f32_16x16x32_bf16(af, bf, acc[nt], 0, 0, 0);
        }
    }
    __syncthreads();   // everyone done reading sX/sW -> safe to alias
    unsigned short* hbuf  = smem + wv * 16 * 72;             // per-wave 16x72
    unsigned short* hbuf2 = smem + (4 + wv) * 16 * 72;
    unsigned short* W2b = sW;                                 // 64x72
    unsigned short* W3b = sW + 64 * 72;                       // 32x72
    for (int i = tid; i < 4096; i += 256)
        W2b[(i >> 6) * 72 + (i & 63)] = f2bf(W2[i]);
    for (int i = tid; i < 2048; i += 256) {
        int n = i >> 6, k = i & 63;
        W3b[n * 72 + k] = (n < 17) ? f2bf(W3[n * 64 + k]) : 0;
    }
    // ---- LN1 in registers (C layout: row=q4+rg, col=nt*16+m), write bf16 A-layout
    #pragma unroll
    for (int rg = 0; rg < 4; ++rg) {
        float h0 = acc[0][rg] + b1v[0], h1 = acc[1][rg] + b1v[1];
        float h2 = acc[2][rg] + b1v[2], h3 = acc[3][rg] + b1v[3];
        float s = (h0 + h1) + (h2 + h3);
        s += __shfl_xor(s, 1); s += __shfl_xor(s, 2);
        s += __shfl_xor(s, 4); s += __shfl_xor(s, 8);
        float mu = s * (1.0f / 64.0f);
        float d0 = h0 - mu, d1 = h1 - mu, d2 = h2 - mu, d3 = h3 - mu;
        float vs = (d0 * d0 + d1 * d1) + (d2 * d2 + d3 * d3);
        vs += __shfl_xor(vs, 1); vs += __shfl_xor(vs, 2);
        vs += __shfl_xor(vs, 4); vs += __shfl_xor(vs, 8);
        float rstd = 1.0f / sqrtf(vs * (1.0f / 64.0f) + 1e-5f);
        float hn0 = d0 * rstd * g1v[0] + be1v[0]; hn0 = fmaxf(hn0, 0.01f * hn0);
        float hn1 = d1 * rstd * g1v[1] + be1v[1]; hn1 = fmaxf(hn1, 0.01f * hn1);
        float hn2 = d2 * rstd * g1v[2] + be1v[2]; hn2 = fmaxf(hn2, 0.01f * hn2);
        float hn3 = d3 * rstd * g1v[3] + be1v[3]; hn3 = fmaxf(hn3, 0.01f * hn3);
        int rr = (q4 + rg) * 72 + m;
        hbuf[rr] = f2bf(hn0); hbuf[rr + 16] = f2bf(hn1);
        hbuf[rr + 32] = f2bf(hn2); hbuf[rr + 48] = f2bf(hn3);
    }
    __syncthreads();   // W2b/W3b staged (hbuf is per-wave, covered too)
    // ---- layer 2 MFMA: K=64, N=64
    f32x4 acc2[4];
    #pragma unroll
    for (int nt = 0; nt < 4; ++nt) acc2[nt] = (f32x4){0.f, 0.f, 0.f, 0.f};
    const unsigned short* a2p = hbuf + m * 72 + kq * 8;
    #pragma unroll
    for (int ks = 0; ks < 2; ++ks) {
        short8 af = *(const short8*)(a2p + ks * 32);
        #pragma unroll
        for (int nt = 0; nt < 4; ++nt) {
            short8 bf = *(const short8*)(W2b + (nt * 16 + m) * 72 + kq * 8 + ks * 32);
            acc2[nt] = __builtin_amdgcn_mfma_f32_16x16x32_bf16(af, bf, acc2[nt], 0, 0, 0);
        }
    }
    // ---- LN2 -> hbuf2 (per-wave, no barrier needed)
    #pragma unroll
    for (int rg = 0; rg < 4; ++rg) {
        float h0 = acc2[0][rg] + b2v[0], h1 = acc2[1][rg] + b2v[1];
        float h2 = acc2[2][rg] + b2v[2], h3 = acc2[3][rg] + b2v[3];
        float s = (h0 + h1) + (h2 + h3);
        s += __shfl_xor(s, 1); s += __shfl_xor(s, 2);
        s += __shfl_xor(s, 4); s += __shfl_xor(s, 8);
        float mu = s * (1.0f / 64.0f);
        float d0 = h0 - mu, d1 = h1 - mu, d2 = h2 - mu, d3 = h3 - mu;
        float vs = (d0 * d0 + d1 * d1) + (d2 * d2 + d3 * d3);
        vs += __shfl_xor(vs, 1); vs += __shfl_xor(vs, 2);
        vs += __shfl_xor(vs, 4); vs += __shfl_xor(vs, 8);
        float rstd = 1.0f / sqrtf(vs * (1.0f / 64.0f) + 1e-5f);
        float hn0 = d0 * rstd * g2v[0] + be2v[0]; hn0 = fmaxf(hn0, 0.01f * hn0);
        float hn1 = d1 * rstd * g2v[1] + be2v[1]; hn1 = fmaxf(hn1, 0.01f * hn1);
        float hn2 = d2 * rstd * g2v[2] + be2v[2]; hn2 = fmaxf(hn2, 0.01f * hn2);
        float hn3 = d3 * rstd * g2v[3] + be2v[3]; hn3 = fmaxf(hn3, 0.01f * hn3);
        int rr = (q4 + rg) * 72 + m;
        hbuf2[rr] = f2bf(hn0); hbuf2[rr + 16] = f2bf(hn1);
        hbuf2[rr + 32] = f2bf(hn2); hbuf2[rr + 48] = f2bf(hn3);
    }
    // ---- layer 3 MFMA: K=64, N=32 (17 used)
    f32x4 acc3[2];
    acc3[0] = (f32x4){0.f, 0.f, 0.f, 0.f};
    acc3[1] = (f32x4){0.f, 0.f, 0.f, 0.f};
    const unsigned short* a3p = hbuf2 + m * 72 + kq * 8;
    #pragma unroll
    for (int ks = 0; ks < 2; ++ks) {
        short8 af = *(const short8*)(a3p + ks * 32);
        #pragma unroll
        for (int nt = 0; nt < 2; ++nt) {
            short8 bf = *(const short8*)(W3b + (nt * 16 + m) * 72 + kq * 8 + ks * 32);
            acc3[nt] = __builtin_amdgcn_mfma_f32_16x16x32_bf16(af, bf, acc3[nt], 0, 0, 0);
        }
    }
    // ---- store (C layout: row=q4+rg, col=nt*16+m)
    #pragma unroll
    for (int nt = 0; nt < 2; ++nt) {
        int c = nt * 16 + m;
        if (c < 17) {
            float b3v = b3[c];
            #pragma unroll
            for (int rg = 0; rg < 4; ++rg) {
                int row = tile * 64 + wv * 16 + q4 + rg;
                float val = acc3[nt][rg] + b3v;
                if (row < 5120) {
                    int cam = row / 2560; int p = row - cam * 2560;
                    sed[((size_t)cam * 2560 + p) * 17 + c] = val;
                } else {
                    int rr = row - 5120; int cam = rr >> 12; int t = rr & 4095;
                    ldf[((size_t)cam * 17 + c) * 4096 + t] = val;
                }
            }
        }
    }
}

// ---------------------------------------------------------------- mask prototypes
__global__ __launch_bounds__(256) void proto_kernel(const float* __restrict__ masks,
                                                    const float* __restrict__ ldf,
                                                    float* __restrict__ proto) {
    int cam = blockIdx.y, m = blockIdx.x;
    const float* M = masks + ((size_t)cam * 16 + m) * 40000;
    float acc[18];
    #pragma unroll
    for (int j = 0; j < 18; ++j) acc[j] = 0.0f;
    for (int t = threadIdx.x; t < 4096; t += 256) {
        int h = t >> 6, w = t & 63;
        int rh = (h * 25) >> 3, rw = (w * 25) >> 3;
        float lv = M[rh * 200 + rw];
        if (lv != 0.0f) {
            acc[17] += lv;
            const float* L = ldf + (size_t)cam * 17 * 4096 + t;
            #pragma unroll
            for (int c = 0; c < 17; ++c) acc[c] = fmaf(lv, L[(size_t)c * 4096], acc[c]);
        }
    }
    __shared__ float red[4][18];
    int lane = threadIdx.x & 63, wv = threadIdx.x >> 6;
    #pragma unroll
    for (int j = 0; j < 18; ++j) {
        float v = acc[j];
        #pragma unroll
        for (int o = 32; o; o >>= 1) v += __shfl_xor(v, o);
        if (lane == 0) red[wv][j] = v;
    }
    __syncthreads();
    if (threadIdx.x < 17) {
        float sacc = red[0][threadIdx.x] + red[1][threadIdx.x] + red[2][threadIdx.x] + red[3][threadIdx.x];
        float ms = red[0][17] + red[1][17] + red[2][17] + red[3][17];
        proto[((size_t)cam * 16 + m) * 17 + threadIdx.x] = sacc / fmaxf(ms, 1e-6f);
    }
}

__device__ __forceinline__ void block_atomic_add(float v, float* target) {
    #pragma unroll
    for (int o = 32; o; o >>= 1) v += __shfl_xor(v, o);
    __shared__ float sred[4];
    int lane = threadIdx.x & 63, wv = threadIdx.x >> 6;
    if (lane == 0) sred[wv] = v;
    __syncthreads();
    if (threadIdx.x == 0) atomicAdd(target, sred[0] + sred[1] + sred[2] + sred[3]);
}

// ---------------------------------------------------------------- BCE loss
__global__ __launch_bounds__(256) void bce_kernel(const float* __restrict__ masks,
                                                  const float* __restrict__ proto,
                                                  const float* __restrict__ fmap,
                                                  float* __restrict__ out) {
    int idx = blockIdx.x * 256 + threadIdx.x;
    int p = idx % P_PIX;
    int rem = idx / P_PIX;
    int m = rem & 15, cam = rem >> 4;
    const float* pr = proto + ((size_t)cam * 16 + m) * 17;
    float sdot = 0;
    #pragma unroll
    for (int c = 0; c < 17; ++c)
        sdot = fmaf(pr[c], fmap[((size_t)cam * 17 + c) * P_PIX + p], sdot);
    float prob = 1.0f / (1.0f + expf(-sdot));
    int px = p & 63, py = p >> 6;
    float src_r = (py + 0.5f) * 5.0f - 0.5f;
    float src_c = (px + 0.5f) * 3.125f - 0.5f;
    int r0 = (int)fminf(fmaxf(floorf(src_r), 0.0f), 199.0f);
    int r1 = min(r0 + 1, 199);
    float wr = fminf(fmaxf(src_r - (float)r0, 0.0f), 1.0f);
    int c0 = (int)fminf(fmaxf(floorf(src_c), 0.0f), 199.0f);
    int c1 = min(c0 + 1, 199);
    float wc = fminf(fmaxf(src_c - (float)c0, 0.0f), 1.0f);
    const float* M = masks + ((size_t)cam * 16 + m) * 40000;
    float v00 = M[r0 * 200 + c0], v01 = M[r0 * 200 + c1];
    float v10 = M[r1 * 200 + c0], v11 = M[r1 * 200 + c1];
    float xr0 = v00 * (1.0f - wr) + v10 * wr;
    float xr1 = v01 * (1.0f - wr) + v11 * wr;
    float frm = xr0 * (1.0f - wc) + xr1 * wc;
    frm = (frm <= 0.5f) ? 0.0f : frm;
    float bce = frm * logf(prob + 1e-8f) + (1.0f - frm) * logf(1.0f - prob + 1e-8f);
    block_atomic_add(bce * (-1.0f / (16.0f * 2560.0f * 2.0f)), out);
}

// ---------------------------------------------------------------- L1 loss
__global__ __launch_bounds__(256) void l1_kernel(const float* __restrict__ fmap,
                                                 const float* __restrict__ sed,
                                                 float* __restrict__ out) {
    int idx = blockIdx.x * 256 + threadIdx.x;
    float ssum = 0;
    if (idx < 2 * P_PIX) {
        int p = idx % P_PIX, cam = idx / P_PIX;
        #pragma unroll
        for (int c = 0; c < 17; ++c) {
            float dv = fmap[((size_t)cam * 17 + c) * P_PIX + p] - sed[((size_t)cam * P_PIX + p) * 17 + c];
            ssum += fabsf(dv);
        }
    }
    block_atomic_add(ssum * (1.0f / (43520.0f * 2.0f)), out);
}

// ================================================================ launch
extern "C" void kernel_launch(void* const* d_in, const int* in_sizes, int n_in,
                              void* d_out, int out_size, void* d_ws, size_t ws_size,
                              hipStream_t stream) {
    const float* voxel_feats = (const float*)d_in[0];
    const float* opacity     = (const float*)d_in[1];
    const float* sam_embd    = (const float*)d_in[2];
    const float* sam_features= (const float*)d_in[3];
    const float* sam_masks   = (const float*)d_in[4];
    const float* viewmat     = (const float*)d_in[5];
    const float* intrins     = (const float*)d_in[6];
    const float* pc_xyz      = (const float*)d_in[7];
    const float* scales      = (const float*)d_in[8];
    const float* rots        = (const float*)d_in[9];
    const float* W1 = (const float*)d_in[10], *b1 = (const float*)d_in[11];
    const float* g1 = (const float*)d_in[12], *be1 = (const float*)d_in[13];
    const float* W2 = (const float*)d_in[14], *b2 = (const float*)d_in[15];
    const float* g2 = (const float*)d_in[16], *be2 = (const float*)d_in[17];
    const float* W3 = (const float*)d_in[18], *b3 = (const float*)d_in[19];
    float* out = (float*)d_out;
    const int N = in_sizes[7] / 3;  // 12800

    char* w = (char*)d_ws;
    size_t off = 0;
    auto alloc = [&](size_t bytes) -> void* {
        off = (off + 255) & ~(size_t)255;
        void* p = w + off; off += bytes; return p;
    };
    int* rnk  = (int*)alloc((size_t)2 * N * sizeof(int));
    unsigned long long* keys = (unsigned long long*)alloc((size_t)2 * N * 8);
    float* params = (float*)alloc((size_t)7 * 2 * N * 4);
    float* pu  = params,           *pv  = params + 2 * N,  *prad = params + 4 * N;
    float* phA = params + 6 * N,   *phC = params + 8 * N,  *pnB  = params + 10 * N;
    float* pop = params + 12 * N;
    float* rec   = (float*)alloc((size_t)2 * N * 24 * 4);
    float* part  = (float*)alloc((size_t)2 * NC * 18 * P_PIX * 4);
    float* tpref = (float*)alloc((size_t)2 * NC * P_PIX * 4);
    float* fmap  = (float*)alloc((size_t)2 * 17 * P_PIX * 4);
    float* sed   = (float*)alloc((size_t)2 * P_PIX * 17 * 4);
    float* ldf   = (float*)alloc((size_t)2 * 17 * 4096 * 4);
    float* proto = (float*)alloc((size_t)2 * 16 * 17 * 4);
    unsigned char* lists = (unsigned char*)alloc((size_t)2 * NC * 40 * CHUNK);
    int* cnts = (int*)alloc((size_t)2 * NC * 40 * sizeof(int));

    init_kernel<<<(2 * N + 255) / 256, 256, 0, stream>>>(rnk, out, 2 * N);
    dim3 gprep((N + 255) / 256, 2);
    prep_kernel<<<gprep, 256, 0, stream>>>(pc_xyz, scales, rots, opacity, viewmat, intrins,
                                           keys, pu, pv, prad, phA, phC, pnB, pop, N);
    dim3 grank((N + 255) / 256, (N + RANK_CHUNK - 1) / RANK_CHUNK, 2);
    rank_kernel<<<grank, 256, 0, stream>>>(keys, rnk, N);
    scatter_kernel<<<gprep, 256, 0, stream>>>(rnk, pu, pv, prad, phA, phC, pnB, pop,
                                              voxel_feats, rec, N);
    build_kernel<<<2 * NC * 40 / 4, 256, 0, stream>>>(rec, lists, cnts, N);
    dim3 gsplat(10, NC, 2);   // 10 row-groups (4 rows) x 64 chunks x 2 cams
    splat_kernel<<<gsplat, 256, 0, stream>>>(rec, lists, cnts, part, N);
    dim3 gtp(P_PIX / 256, 2);
    tpref_kernel<<<gtp, 256, 0, stream>>>(part, tpref);
    combine_kernel<<<(2 * 17 * P_PIX + 255) / 256, 256, 0, stream>>>(part, tpref, fmap);
    mlp_kernel<<<208, 256, 0, stream>>>(sam_embd, sam_features, W1, b1, g1, be1,
                                        W2, b2, g2, be2, W3, b3, sed, ldf);
    dim3 gproto(16, 2);
    proto_kernel<<<gproto, 256, 0, stream>>>(sam_masks, ldf, proto);
    bce_kernel<<<(2 * 16 * P_PIX) / 256, 256, 0, stream>>>(sam_masks, proto, fmap, out);
    l1_kernel<<<(2 * P_PIX + 255) / 256, 256, 0, stream>>>(fmap, sed, out);
}

// Round 5
// 233.454 us; speedup vs baseline: 1.5761x; 1.0121x over previous
//
#include <hip/hip_runtime.h>
#include <math.h>

#define NPTS   12800
#define P_PIX  2560
#define NC     32          // compositing chunks (NPTS/NC = 400 pts/chunk)
#define CHUNK  400
#define RANK_CHUNK 800
#define RT     4           // rank keys per thread
#define MLP_PITCH 264      // ushorts per LDS row (256 + 8 pad)

typedef short short8 __attribute__((ext_vector_type(8)));
typedef float f32x4 __attribute__((ext_vector_type(4)));
typedef float f32x2 __attribute__((ext_vector_type(2)));

__device__ __forceinline__ unsigned short f2bf(float f) {
    unsigned int u = __float_as_uint(f);
    u += 0x7fffu + ((u >> 16) & 1u);   // RNE
    return (unsigned short)(u >> 16);
}

// ---------------------------------------------------------------- per-point projection (+init)
__global__ __launch_bounds__(256) void prep_kernel(
    const float* __restrict__ xyz, const float* __restrict__ scales,
    const float* __restrict__ rots, const float* __restrict__ opacity,
    const float* __restrict__ viewmat, const float* __restrict__ intrins,
    unsigned long long* __restrict__ keys,
    float* __restrict__ pu, float* __restrict__ pv, float* __restrict__ prad,
    float* __restrict__ phA, float* __restrict__ phC, float* __restrict__ pnB,
    float* __restrict__ pop, int* __restrict__ rnk, float* __restrict__ out, int N) {
    int cam = blockIdx.y;
    int i = blockIdx.x * 256 + threadIdx.x;
    if (i >= N) return;
    int idx = cam * N + i;
    rnk[idx] = 0;
    if (idx == 0) out[0] = 0.0f;
    const float* vm = viewmat + cam * 16;
    const float* it = intrins + cam * 4;
    float fx = it[0], fy = it[1], cx = it[2], cy = it[3];
    float R00 = vm[0], R01 = vm[1], R02 = vm[2], t0 = vm[3];
    float R10 = vm[4], R11 = vm[5], R12 = vm[6], t1 = vm[7];
    float R20 = vm[8], R21 = vm[9], R22 = vm[10], t2 = vm[11];
    float X = xyz[i * 3], Y = xyz[i * 3 + 1], Z = xyz[i * 3 + 2];
    float x = R00 * X + R01 * Y + R02 * Z + t0;
    float y = R10 * X + R11 * Y + R12 * Z + t1;
    float z = R20 * X + R21 * Y + R22 * Z + t2;
    float zc = fmaxf(z, 0.001f);
    float iz = 1.0f / zc;
    float u = fx * x * iz + cx;
    float v = fy * y * iz + cy;
    float qw = rots[i * 4], qx = rots[i * 4 + 1], qy = rots[i * 4 + 2], qz = rots[i * 4 + 3];
    float qn = 1.0f / sqrtf(qw * qw + qx * qx + qy * qy + qz * qz);
    qw *= qn; qx *= qn; qy *= qn; qz *= qn;
    float s0 = expf(scales[i * 3]), s1 = expf(scales[i * 3 + 1]), s2 = expf(scales[i * 3 + 2]);
    float Rq[3][3] = {
        {1 - 2 * (qy * qy + qz * qz), 2 * (qx * qy - qw * qz), 2 * (qx * qz + qw * qy)},
        {2 * (qx * qy + qw * qz), 1 - 2 * (qx * qx + qz * qz), 2 * (qy * qz - qw * qx)},
        {2 * (qx * qz - qw * qy), 2 * (qy * qz + qw * qx), 1 - 2 * (qx * qx + qy * qy)}};
    float M[3][3];
    #pragma unroll
    for (int r = 0; r < 3; ++r) { M[r][0] = Rq[r][0] * s0; M[r][1] = Rq[r][1] * s1; M[r][2] = Rq[r][2] * s2; }
    float c3[3][3];
    #pragma unroll
    for (int a = 0; a < 3; ++a)
        #pragma unroll
        for (int b = 0; b < 3; ++b)
            c3[a][b] = M[a][0] * M[b][0] + M[a][1] * M[b][1] + M[a][2] * M[b][2];
    float Rw[3][3] = {{R00, R01, R02}, {R10, R11, R12}, {R20, R21, R22}};
    float Wt[3][3];
    #pragma unroll
    for (int a = 0; a < 3; ++a)
        #pragma unroll
        for (int b = 0; b < 3; ++b)
            Wt[a][b] = Rw[a][0] * c3[0][b] + Rw[a][1] * c3[1][b] + Rw[a][2] * c3[2][b];
    float cw[3][3];
    #pragma unroll
    for (int a = 0; a < 3; ++a)
        #pragma unroll
        for (int b = 0; b < 3; ++b)
            cw[a][b] = Wt[a][0] * Rw[b][0] + Wt[a][1] * Rw[b][1] + Wt[a][2] * Rw[b][2];
    float j00 = fx * iz, j02 = -fx * x * iz * iz;
    float j11 = fy * iz, j12 = -fy * y * iz * iz;
    float c00 = j00 * j00 * cw[0][0] + 2.0f * j00 * j02 * cw[0][2] + j02 * j02 * cw[2][2];
    float c01 = j00 * j11 * cw[0][1] + j00 * j12 * cw[0][2] + j02 * j11 * cw[2][1] + j02 * j12 * cw[2][2];
    float c11 = j11 * j11 * cw[1][1] + 2.0f * j11 * j12 * cw[1][2] + j12 * j12 * cw[2][2];
    float a = c00 + 0.3f, bq = c01, cc = c11 + 0.3f;
    float det = a * cc - bq * bq;
    float A = cc / det, Bc = -bq / det, Cc = a / det;
    float lmin = 0.5f * ((A + Cc) - sqrtf((A - Cc) * (A - Cc) + 4.0f * Bc * Bc));
    lmin = fmaxf(lmin, 1e-20f);
    float opv = (z > 0.2f) ? opacity[i] : 0.0f;
    float rad = -1.0f;
    if (opv > 0.0f) {
        float tcut = logf(opv) + 18.42f;  // ln(op * 1e8)
        if (tcut > 0.0f) rad = sqrtf(2.0f * tcut / lmin);
    }
    pu[idx] = u; pv[idx] = v; prad[idx] = rad;
    phA[idx] = -0.5f * A; phC[idx] = -0.5f * Cc; pnB[idx] = -Bc;
    pop[idx] = opv;
    unsigned int zb = __float_as_uint(z);
    zb = (zb & 0x80000000u) ? ~zb : (zb | 0x80000000u);
    keys[idx] = ((unsigned long long)zb << 32) | (unsigned int)i;
}

// ---------------------------------------------------------------- stable rank, RT keys/thread
__global__ __launch_bounds__(256) void rank_kernel(const unsigned long long* __restrict__ keys,
                                                   int* __restrict__ rnk, int N) {
    __shared__ unsigned long long sk[RANK_CHUNK];
    int cam = blockIdx.z;
    const unsigned long long* K = keys + (size_t)cam * N;
    int jbase = blockIdx.y * RANK_CHUNK;
    int jcnt = min(RANK_CHUNK, N - jbase);
    for (int t = threadIdx.x; t < jcnt; t += 256) sk[t] = K[jbase + t];
    __syncthreads();
    int i0 = blockIdx.x * (256 * RT) + threadIdx.x;
    unsigned long long ki[RT];
    int cnt[RT];
    #pragma unroll
    for (int t = 0; t < RT; ++t) {
        int i = i0 + t * 256;
        ki[t] = (i < N) ? K[i] : 0xFFFFFFFFFFFFFFFFull;
        cnt[t] = 0;
    }
    #pragma unroll 4
    for (int j = 0; j < jcnt; ++j) {
        unsigned long long kj = sk[j];
        #pragma unroll
        for (int t = 0; t < RT; ++t) cnt[t] += (kj < ki[t]) ? 1 : 0;
    }
    #pragma unroll
    for (int t = 0; t < RT; ++t) {
        int i = i0 + t * 256;
        if (i < N && cnt[t]) atomicAdd(rnk + (size_t)cam * N + i, cnt[t]);
    }
}

// ---------------------------------------------------------------- scatter into sorted records
// layout: [u, v, op, hA | hC, nB, f0, f1 | f2..f5 | f6..f9 | f10..f13 | f14,f15,f16,0] = 24 floats
__global__ __launch_bounds__(256) void scatter_kernel(
    const int* __restrict__ rnk,
    const float* __restrict__ pu, const float* __restrict__ pv, const float* __restrict__ prad,
    const float* __restrict__ phA, const float* __restrict__ phC, const float* __restrict__ pnB,
    const float* __restrict__ pop,
    const float* __restrict__ feats, float* __restrict__ rec, float2* __restrict__ vr, int N) {
    int cam = blockIdx.y;
    int i = blockIdx.x * 256 + threadIdx.x;
    if (i >= N) return;
    int idx = cam * N + i;
    int r = rnk[idx];
    float* d = rec + ((size_t)cam * N + r) * 24;
    d[0] = pu[idx]; d[1] = pv[idx]; d[2] = pop[idx]; d[3] = phA[idx];
    d[4] = phC[idx]; d[5] = pnB[idx];
    const float* f = feats + (size_t)i * 17;
    #pragma unroll
    for (int c = 0; c < 17; ++c) d[6 + c] = f[c];
    d[23] = 0.0f;
    vr[(size_t)cam * N + r] = make_float2(pv[idx], prad[idx]);
}

// ---------------------------------------------------------------- build per-(cam,chunk,row) pass lists
__global__ __launch_bounds__(256) void build_kernel(const float2* __restrict__ vr,
                                                    unsigned short* __restrict__ lists,
                                                    int* __restrict__ cnts, int N) {
    int gid = blockIdx.x * 4 + (threadIdx.x >> 6);   // list id
    int lane = threadIdx.x & 63;
    int cam = gid / (NC * 40);
    int rem = gid - cam * (NC * 40);
    int ch = rem / 40, row = rem - ch * 40;
    const float2* V = vr + (size_t)cam * N + ch * CHUNK;
    unsigned short* L = lists + (size_t)gid * CHUNK;
    float py = (float)row;
    int cnt = 0;
    for (int g = 0; g < CHUNK; g += 64) {
        int n = g + lane;
        bool pass = false;
        if (n < CHUNK) {
            float2 t = V[n];
            pass = fabsf(t.x - py) <= t.y + 0.01f;
        }
        unsigned long long mask = __ballot(pass);
        int pre = __popcll(mask & ((1ull << lane) - 1ull));
        if (pass) L[cnt + pre] = (unsigned short)n;
        cnt += __popcll(mask);
    }
    if (lane == 0) cnts[gid] = cnt;
}

// ---------------------------------------------------------------- chunked alpha compositing (list-driven, packed f32)
__global__ __launch_bounds__(256) void splat_kernel(const float* __restrict__ rec,
                                                    const unsigned short* __restrict__ lists,
                                                    const int* __restrict__ cnts,
                                                    float* __restrict__ part, int N) {
    __shared__ __align__(16) float4 sRec[CHUNK * 6];   // 38.4 KB
    __shared__ unsigned short sList[4 * CHUNK];
    __shared__ int sCnt[4];
    int cam = blockIdx.z, ch = blockIdx.y, pg = blockIdx.x;  // pg 0..9, 4 rows per block
    int tid = threadIdx.x, lane = tid & 63, wv = tid >> 6;
    const float4* src = (const float4*)(rec + ((size_t)cam * N + ch * CHUNK) * 24);
    for (int t = tid; t < CHUNK * 6; t += 256) sRec[t] = src[t];
    int lid0 = (cam * NC + ch) * 40 + pg * 4;
    const unsigned int* Lb = (const unsigned int*)(lists + (size_t)lid0 * CHUNK);
    unsigned int* sL = (unsigned int*)sList;
    for (int t = tid; t < 2 * CHUNK; t += 256) sL[t] = Lb[t];
    if (tid < 4) sCnt[tid] = cnts[lid0 + tid];
    __syncthreads();
    int row = pg * 4 + wv;
    int cnt = sCnt[wv];
    float px = (float)lane, py = (float)row;
    float T = 1.0f;
    f32x2 acc[9];
    #pragma unroll
    for (int j = 0; j < 9; ++j) acc[j] = (f32x2){0.f, 0.f};
    const unsigned short* myL = sList + wv * CHUNK;
    for (int i = 0; i < cnt; ++i) {
        int n = myL[i];                        // wave-uniform -> LDS broadcast
        const float4* rp = sRec + n * 6;
        float4 q0 = rp[0];   // u, v, op, hA
        float4 q1 = rp[1];   // hC, nB, f0, f1
        float dx = q0.x - px, dy = q0.y - py;
        float t1 = (q1.y * dx) * dy;
        t1 = fmaf(q1.x * dy, dy, t1);
        float power = fminf(fmaf(q0.w * dx, dx, t1), 0.0f);
        float alpha = fminf(0.99f, q0.z * __expf(power));
        float w = alpha * T;
        f32x2 w2 = (f32x2){w, w};
        float4 q2 = rp[2], q3 = rp[3], q4 = rp[4], q5 = rp[5];
        acc[0] += w2 * (f32x2){q1.z, q1.w};
        acc[1] += w2 * (f32x2){q2.x, q2.y};
        acc[2] += w2 * (f32x2){q2.z, q2.w};
        acc[3] += w2 * (f32x2){q3.x, q3.y};
        acc[4] += w2 * (f32x2){q3.z, q3.w};
        acc[5] += w2 * (f32x2){q4.x, q4.y};
        acc[6] += w2 * (f32x2){q4.z, q4.w};
        acc[7] += w2 * (f32x2){q5.x, q5.y};
        acc[8] += w2 * (f32x2){q5.z, q5.w};
        T *= (1.0f - alpha);
    }
    int p0 = row * 64 + lane;
    size_t base = ((size_t)(cam * NC + ch) * 18) * P_PIX;
    part[base + p0] = T;
    #pragma unroll
    for (int j = 0; j < 8; ++j) {
        part[base + (size_t)(1 + 2 * j) * P_PIX + p0] = acc[j][0];
        part[base + (size_t)(2 + 2 * j) * P_PIX + p0] = acc[j][1];
    }
    part[base + (size_t)17 * P_PIX + p0] = acc[8][0];
}

// ---------------------------------------------------------------- combine chunks -> fmap (T-prefix in-register)
__global__ __launch_bounds__(256) void combine_kernel(const float* __restrict__ part,
                                                      float* __restrict__ fmap) {
    int idx = blockIdx.x * 256 + threadIdx.x;
    if (idx >= 2 * 17 * P_PIX) return;
    int p = idx % P_PIX;
    int rem = idx / P_PIX;
    int c = rem % 17;
    int cam = rem / 17;
    float acc = 0.0f, Tp = 1.0f;
    #pragma unroll 8
    for (int k = 0; k < NC; ++k) {
        size_t base = ((size_t)(cam * NC + k) * 18) * P_PIX + p;
        float Tk = part[base];
        float S  = part[base + (size_t)(1 + c) * P_PIX];
        acc = fmaf(Tp, S, acc);
        Tp *= Tk;
    }
    fmap[((size_t)cam * 17 + c) * P_PIX + p] = acc;
}

// ---------------------------------------------------------------- MLP: MFMA all 3 layers
__global__ __launch_bounds__(256, 2) void mlp_kernel(
    const float* __restrict__ embd, const float* __restrict__ sfeat,
    const float* __restrict__ W1, const float* __restrict__ b1,
    const float* __restrict__ g1, const float* __restrict__ be1,
    const float* __restrict__ W2, const float* __restrict__ b2,
    const float* __restrict__ g2, const float* __restrict__ be2,
    const float* __restrict__ W3, const float* __restrict__ b3,
    float* __restrict__ sed, float* __restrict__ ldf) {
    __shared__ __align__(16) unsigned short smem[2 * 64 * MLP_PITCH];
    unsigned short* sX = smem;
    unsigned short* sW = smem + 64 * MLP_PITCH;
    int tid = threadIdx.x, lane = tid & 63, wv = tid >> 6;
    int m = lane & 15, kq = lane >> 4, q4 = kq * 4;
    int tile = blockIdx.x;
    const float* xbase;
    if (tile < 80) {
        int cam = tile / 40; int r = tile - cam * 40;
        int ri = (r * 8) / 5;  // floor(r*64/40)
        xbase = embd + (size_t)cam * 256 * 4096 + ri * 64;
    } else {
        int tt = tile - 80; int cam = tt >> 6;
        xbase = sfeat + (size_t)cam * 256 * 4096 + (tt & 63) * 64;
    }
    const float4* xf4 = (const float4*)xbase;
    for (int idx = tid; idx < 4096; idx += 256) {
        int k = idx >> 4, q = idx & 15;
        float4 xv = xf4[(size_t)k * 1024 + q];
        int r = q * 4;
        sX[(r + 0) * MLP_PITCH + k] = f2bf(xv.x);
        sX[(r + 1) * MLP_PITCH + k] = f2bf(xv.y);
        sX[(r + 2) * MLP_PITCH + k] = f2bf(xv.z);
        sX[(r + 3) * MLP_PITCH + k] = f2bf(xv.w);
    }
    const float4* wf4 = (const float4*)W1;
    for (int idx = tid; idx < 4096; idx += 256) {
        float4 wvv = wf4[idx];
        int n = idx >> 6, kk = (idx & 63) * 4;
        uint2 pk;
        pk.x = (unsigned int)f2bf(wvv.x) | ((unsigned int)f2bf(wvv.y) << 16);
        pk.y = (unsigned int)f2bf(wvv.z) | ((unsigned int)f2bf(wvv.w) << 16);
        *(uint2*)&sW[n * MLP_PITCH + kk] = pk;
    }
    float b1v[4], g1v[4], be1v[4], b2v[4], g2v[4], be2v[4];
    #pragma unroll
    for (int nt = 0; nt < 4; ++nt) {
        int c = nt * 16 + m;
        b1v[nt] = b1[c]; g1v[nt] = g1[c]; be1v[nt] = be1[c];
        b2v[nt] = b2[c]; g2v[nt] = g2[c]; be2v[nt] = be2[c];
    }
    __syncthreads();
    f32x4 acc[4];
    #pragma unroll
    for (int nt = 0; nt < 4; ++nt) acc[nt] = (f32x4){0.f, 0.f, 0.f, 0.f};
    const unsigned short* aptr = sX + (wv * 16 + m) * MLP_PITCH + kq * 8;
    const unsigned short* bptr = sW + m * MLP_PITCH + kq * 8;
    #pragma unroll
    for (int ks = 0; ks < 8; ++ks) {
        short8 af = *(const short8*)(aptr + ks * 32);
        #pragma unroll
        for (int nt = 0; nt < 4; ++nt) {
            short8 bf = *(const short8*)(bptr + nt * 16 * MLP_PITCH + ks * 32);
            acc[nt] = __builtin_amdgcn_mfma_f32_16x16x32_bf16(af, bf, acc[nt], 0, 0, 0);
        }
    }
    __syncthreads();   // done reading sX/sW -> safe to alias
    unsigned short* hbuf  = smem + wv * 16 * 72;
    unsigned short* hbuf2 = smem + (4 + wv) * 16 * 72;
    unsigned short* W2b = sW;
    unsigned short* W3b = sW + 64 * 72;
    for (int i = tid; i < 4096; i += 256)
        W2b[(i >> 6) * 72 + (i & 63)] = f2bf(W2[i]);
    for (int i = tid; i < 2048; i += 256) {
        int n = i >> 6, k = i & 63;
        W3b[n * 72 + k] = (n < 17) ? f2bf(W3[n * 64 + k]) : 0;
    }
    #pragma unroll
    for (int rg = 0; rg < 4; ++rg) {
        float h0 = acc[0][rg] + b1v[0], h1 = acc[1][rg] + b1v[1];
        float h2 = acc[2][rg] + b1v[2], h3 = acc[3][rg] + b1v[3];
        float s = (h0 + h1) + (h2 + h3);
        s += __shfl_xor(s, 1); s += __shfl_xor(s, 2);
        s += __shfl_xor(s, 4); s += __shfl_xor(s, 8);
        float mu = s * (1.0f / 64.0f);
        float d0 = h0 - mu, d1 = h1 - mu, d2 = h2 - mu, d3 = h3 - mu;
        float vs = (d0 * d0 + d1 * d1) + (d2 * d2 + d3 * d3);
        vs += __shfl_xor(vs, 1); vs += __shfl_xor(vs, 2);
        vs += __shfl_xor(vs, 4); vs += __shfl_xor(vs, 8);
        float rstd = 1.0f / sqrtf(vs * (1.0f / 64.0f) + 1e-5f);
        float hn0 = d0 * rstd * g1v[0] + be1v[0]; hn0 = fmaxf(hn0, 0.01f * hn0);
        float hn1 = d1 * rstd * g1v[1] + be1v[1]; hn1 = fmaxf(hn1, 0.01f * hn1);
        float hn2 = d2 * rstd * g1v[2] + be1v[2]; hn2 = fmaxf(hn2, 0.01f * hn2);
        float hn3 = d3 * rstd * g1v[3] + be1v[3]; hn3 = fmaxf(hn3, 0.01f * hn3);
        int rr = (q4 + rg) * 72 + m;
        hbuf[rr] = f2bf(hn0); hbuf[rr + 16] = f2bf(hn1);
        hbuf[rr + 32] = f2bf(hn2); hbuf[rr + 48] = f2bf(hn3);
    }
    __syncthreads();
    f32x4 acc2[4];
    #pragma unroll
    for (int nt = 0; nt < 4; ++nt) acc2[nt] = (f32x4){0.f, 0.f, 0.f, 0.f};
    const unsigned short* a2p = hbuf + m * 72 + kq * 8;
    #pragma unroll
    for (int ks = 0; ks < 2; ++ks) {
        short8 af = *(const short8*)(a2p + ks * 32);
        #pragma unroll
        for (int nt = 0; nt < 4; ++nt) {
            short8 bf = *(const short8*)(W2b + (nt * 16 + m) * 72 + kq * 8 + ks * 32);
            acc2[nt] = __builtin_amdgcn_mfma_f32_16x16x32_bf16(af, bf, acc2[nt], 0, 0, 0);
        }
    }
    #pragma unroll
    for (int rg = 0; rg < 4; ++rg) {
        float h0 = acc2[0][rg] + b2v[0], h1 = acc2[1][rg] + b2v[1];
        float h2 = acc2[2][rg] + b2v[2], h3 = acc2[3][rg] + b2v[3];
        float s = (h0 + h1) + (h2 + h3);
        s += __shfl_xor(s, 1); s += __shfl_xor(s, 2);
        s += __shfl_xor(s, 4); s += __shfl_xor(s, 8);
        float mu = s * (1.0f / 64.0f);
        float d0 = h0 - mu, d1 = h1 - mu, d2 = h2 - mu, d3 = h3 - mu;
        float vs = (d0 * d0 + d1 * d1) + (d2 * d2 + d3 * d3);
        vs += __shfl_xor(vs, 1); vs += __shfl_xor(vs, 2);
        vs += __shfl_xor(vs, 4); vs += __shfl_xor(vs, 8);
        float rstd = 1.0f / sqrtf(vs * (1.0f / 64.0f) + 1e-5f);
        float hn0 = d0 * rstd * g2v[0] + be2v[0]; hn0 = fmaxf(hn0, 0.01f * hn0);
        float hn1 = d1 * rstd * g2v[1] + be2v[1]; hn1 = fmaxf(hn1, 0.01f * hn1);
        float hn2 = d2 * rstd * g2v[2] + be2v[2]; hn2 = fmaxf(hn2, 0.01f * hn2);
        float hn3 = d3 * rstd * g2v[3] + be2v[3]; hn3 = fmaxf(hn3, 0.01f * hn3);
        int rr = (q4 + rg) * 72 + m;
        hbuf2[rr] = f2bf(hn0); hbuf2[rr + 16] = f2bf(hn1);
        hbuf2[rr + 32] = f2bf(hn2); hbuf2[rr + 48] = f2bf(hn3);
    }
    f32x4 acc3[2];
    acc3[0] = (f32x4){0.f, 0.f, 0.f, 0.f};
    acc3[1] = (f32x4){0.f, 0.f, 0.f, 0.f};
    const unsigned short* a3p = hbuf2 + m * 72 + kq * 8;
    #pragma unroll
    for (int ks = 0; ks < 2; ++ks) {
        short8 af = *(const short8*)(a3p + ks * 32);
        #pragma unroll
        for (int nt = 0; nt < 2; ++nt) {
            short8 bf = *(const short8*)(W3b + (nt * 16 + m) * 72 + kq * 8 + ks * 32);
            acc3[nt] = __builtin_amdgcn_mfma_f32_16x16x32_bf16(af, bf, acc3[nt], 0, 0, 0);
        }
    }
    #pragma unroll
    for (int nt = 0; nt < 2; ++nt) {
        int c = nt * 16 + m;
        if (c < 17) {
            float b3v = b3[c];
            #pragma unroll
            for (int rg = 0; rg < 4; ++rg) {
                int row = tile * 64 + wv * 16 + q4 + rg;
                float val = acc3[nt][rg] + b3v;
                if (row < 5120) {
                    int cam = row / 2560; int p = row - cam * 2560;
                    sed[((size_t)cam * 2560 + p) * 17 + c] = val;
                } else {
                    int rr = row - 5120; int cam = rr >> 12; int t = rr & 4095;
                    ldf[((size_t)cam * 17 + c) * 4096 + t] = val;
                }
            }
        }
    }
}

// ---------------------------------------------------------------- mask prototypes
__global__ __launch_bounds__(256) void proto_kernel(const float* __restrict__ masks,
                                                    const float* __restrict__ ldf,
                                                    float* __restrict__ proto) {
    int cam = blockIdx.y, m = blockIdx.x;
    const float* M = masks + ((size_t)cam * 16 + m) * 40000;
    float acc[18];
    #pragma unroll
    for (int j = 0; j < 18; ++j) acc[j] = 0.0f;
    for (int t = threadIdx.x; t < 4096; t += 256) {
        int h = t >> 6, w = t & 63;
        int rh = (h * 25) >> 3, rw = (w * 25) >> 3;
        float lv = M[rh * 200 + rw];
        if (lv != 0.0f) {
            acc[17] += lv;
            const float* L = ldf + (size_t)cam * 17 * 4096 + t;
            #pragma unroll
            for (int c = 0; c < 17; ++c) acc[c] = fmaf(lv, L[(size_t)c * 4096], acc[c]);
        }
    }
    __shared__ float red[4][18];
    int lane = threadIdx.x & 63, wv = threadIdx.x >> 6;
    #pragma unroll
    for (int j = 0; j < 18; ++j) {
        float v = acc[j];
        #pragma unroll
        for (int o = 32; o; o >>= 1) v += __shfl_xor(v, o);
        if (lane == 0) red[wv][j] = v;
    }
    __syncthreads();
    if (threadIdx.x < 17) {
        float sacc = red[0][threadIdx.x] + red[1][threadIdx.x] + red[2][threadIdx.x] + red[3][threadIdx.x];
        float ms = red[0][17] + red[1][17] + red[2][17] + red[3][17];
        proto[((size_t)cam * 16 + m) * 17 + threadIdx.x] = sacc / fmaxf(ms, 1e-6f);
    }
}

__device__ __forceinline__ void block_atomic_add(float v, float* target) {
    #pragma unroll
    for (int o = 32; o; o >>= 1) v += __shfl_xor(v, o);
    __shared__ float sred[4];
    int lane = threadIdx.x & 63, wv = threadIdx.x >> 6;
    if (lane == 0) sred[wv] = v;
    __syncthreads();
    if (threadIdx.x == 0) atomicAdd(target, sred[0] + sred[1] + sred[2] + sred[3]);
}

// ---------------------------------------------------------------- BCE + L1 loss (fused)
__global__ __launch_bounds__(256) void bce_kernel(const float* __restrict__ masks,
                                                  const float* __restrict__ proto,
                                                  const float* __restrict__ fmap,
                                                  const float* __restrict__ sed,
                                                  float* __restrict__ out) {
    int idx = blockIdx.x * 256 + threadIdx.x;
    int p = idx % P_PIX;
    int rem = idx / P_PIX;
    int m = rem & 15, cam = rem >> 4;
    const float* pr = proto + ((size_t)cam * 16 + m) * 17;
    float f[17];
    #pragma unroll
    for (int c = 0; c < 17; ++c) f[c] = fmap[((size_t)cam * 17 + c) * P_PIX + p];
    float sdot = 0;
    #pragma unroll
    for (int c = 0; c < 17; ++c) sdot = fmaf(pr[c], f[c], sdot);
    float prob = 1.0f / (1.0f + __expf(-sdot));
    int px = p & 63, py = p >> 6;
    float src_r = (py + 0.5f) * 5.0f - 0.5f;
    float src_c = (px + 0.5f) * 3.125f - 0.5f;
    int r0 = (int)fminf(fmaxf(floorf(src_r), 0.0f), 199.0f);
    int r1 = min(r0 + 1, 199);
    float wr = fminf(fmaxf(src_r - (float)r0, 0.0f), 1.0f);
    int c0 = (int)fminf(fmaxf(floorf(src_c), 0.0f), 199.0f);
    int c1 = min(c0 + 1, 199);
    float wc = fminf(fmaxf(src_c - (float)c0, 0.0f), 1.0f);
    const float* M = masks + ((size_t)cam * 16 + m) * 40000;
    float v00 = M[r0 * 200 + c0], v01 = M[r0 * 200 + c1];
    float v10 = M[r1 * 200 + c0], v11 = M[r1 * 200 + c1];
    float xr0 = v00 * (1.0f - wr) + v10 * wr;
    float xr1 = v01 * (1.0f - wr) + v11 * wr;
    float frm = xr0 * (1.0f - wc) + xr1 * wc;
    frm = (frm <= 0.5f) ? 0.0f : frm;
    float bce = frm * __logf(prob + 1e-8f) + (1.0f - frm) * __logf(1.0f - prob + 1e-8f);
    float val = bce * (-1.0f / (16.0f * 2560.0f * 2.0f));
    if (m == 0) {   // L1 term, once per (cam, p)
        float ssum = 0.0f;
        const float* sp = sed + ((size_t)cam * P_PIX + p) * 17;
        #pragma unroll
        for (int c = 0; c < 17; ++c) ssum += fabsf(f[c] - sp[c]);
        val += ssum * (1.0f / (43520.0f * 2.0f));
    }
    block_atomic_add(val, out);
}

// ================================================================ launch
extern "C" void kernel_launch(void* const* d_in, const int* in_sizes, int n_in,
                              void* d_out, int out_size, void* d_ws, size_t ws_size,
                              hipStream_t stream) {
    const float* voxel_feats = (const float*)d_in[0];
    const float* opacity     = (const float*)d_in[1];
    const float* sam_embd    = (const float*)d_in[2];
    const float* sam_features= (const float*)d_in[3];
    const float* sam_masks   = (const float*)d_in[4];
    const float* viewmat     = (const float*)d_in[5];
    const float* intrins     = (const float*)d_in[6];
    const float* pc_xyz      = (const float*)d_in[7];
    const float* scales      = (const float*)d_in[8];
    const float* rots        = (const float*)d_in[9];
    const float* W1 = (const float*)d_in[10], *b1 = (const float*)d_in[11];
    const float* g1 = (const float*)d_in[12], *be1 = (const float*)d_in[13];
    const float* W2 = (const float*)d_in[14], *b2 = (const float*)d_in[15];
    const float* g2 = (const float*)d_in[16], *be2 = (const float*)d_in[17];
    const float* W3 = (const float*)d_in[18], *b3 = (const float*)d_in[19];
    float* out = (float*)d_out;
    const int N = in_sizes[7] / 3;  // 12800

    char* w = (char*)d_ws;
    size_t off = 0;
    auto alloc = [&](size_t bytes) -> void* {
        off = (off + 255) & ~(size_t)255;
        void* p = w + off; off += bytes; return p;
    };
    int* rnk  = (int*)alloc((size_t)2 * N * sizeof(int));
    unsigned long long* keys = (unsigned long long*)alloc((size_t)2 * N * 8);
    float* params = (float*)alloc((size_t)7 * 2 * N * 4);
    float* pu  = params,           *pv  = params + 2 * N,  *prad = params + 4 * N;
    float* phA = params + 6 * N,   *phC = params + 8 * N,  *pnB  = params + 10 * N;
    float* pop = params + 12 * N;
    float* rec   = (float*)alloc((size_t)2 * N * 24 * 4);
    float2* vr   = (float2*)alloc((size_t)2 * N * 8);
    float* part  = (float*)alloc((size_t)2 * NC * 18 * P_PIX * 4);
    float* fmap  = (float*)alloc((size_t)2 * 17 * P_PIX * 4);
    float* sed   = (float*)alloc((size_t)2 * P_PIX * 17 * 4);
    float* ldf   = (float*)alloc((size_t)2 * 17 * 4096 * 4);
    float* proto = (float*)alloc((size_t)2 * 16 * 17 * 4);
    unsigned short* lists = (unsigned short*)alloc((size_t)2 * NC * 40 * CHUNK * 2);
    int* cnts = (int*)alloc((size_t)2 * NC * 40 * sizeof(int));

    dim3 gprep((N + 255) / 256, 2);
    prep_kernel<<<gprep, 256, 0, stream>>>(pc_xyz, scales, rots, opacity, viewmat, intrins,
                                           keys, pu, pv, prad, phA, phC, pnB, pop, rnk, out, N);
    dim3 grank((N + 256 * RT - 1) / (256 * RT), (N + RANK_CHUNK - 1) / RANK_CHUNK, 2);
    rank_kernel<<<grank, 256, 0, stream>>>(keys, rnk, N);
    scatter_kernel<<<gprep, 256, 0, stream>>>(rnk, pu, pv, prad, phA, phC, pnB, pop,
                                              voxel_feats, rec, vr, N);
    build_kernel<<<2 * NC * 40 / 4, 256, 0, stream>>>(vr, lists, cnts, N);
    dim3 gsplat(10, NC, 2);
    splat_kernel<<<gsplat, 256, 0, stream>>>(rec, lists, cnts, part, N);
    mlp_kernel<<<208, 256, 0, stream>>>(sam_embd, sam_features, W1, b1, g1, be1,
                                        W2, b2, g2, be2, W3, b3, sed, ldf);
    combine_kernel<<<(2 * 17 * P_PIX + 255) / 256, 256, 0, stream>>>(part, fmap);
    dim3 gproto(16, 2);
    proto_kernel<<<gproto, 256, 0, stream>>>(sam_masks, ldf, proto);
    bce_kernel<<<(2 * 16 * P_PIX) / 256, 256, 0, stream>>>(sam_masks, proto, fmap, sed, out);
}